// Round 9
// baseline (698.658 us; speedup 1.0000x reference)
//
#include <hip/hip_runtime.h>

typedef unsigned short u16;
typedef unsigned int u32;
typedef __attribute__((ext_vector_type(8))) short short8;
typedef __attribute__((ext_vector_type(16))) float f32x16;

#define BB 4
#define NN 128
#define DD 256
#define DFF 1024

__device__ __forceinline__ u16 f2b(float f) {
  union { float f; u32 u; } c; c.f = f;
  u32 x = c.u;
  return (u16)((x + 0x7FFFu + ((x >> 16) & 1u)) >> 16);
}
__device__ __forceinline__ float b2f(u16 u) {
  union { u32 u; float f; } c; c.u = ((u32)u) << 16;
  return c.f;
}

__device__ __forceinline__ void gld_lds16(const void* g, void* l) {
  __builtin_amdgcn_global_load_lds(
      (const __attribute__((address_space(1))) unsigned int*)g,
      (__attribute__((address_space(3))) unsigned int*)l, 16, 0, 0);
}

// ---------------- K0: transpose+convert FFN weights (graph AND node) to bf16 ----
__global__ void k0_conv(const float* __restrict__ Wgf1, const float* __restrict__ Wgf2,
                        const float* __restrict__ W1n, const float* __restrict__ W2n,
                        u16* __restrict__ W1t, u16* __restrict__ W2c,
                        u16* __restrict__ W1tn, u16* __restrict__ W2cn) {
  int gi = blockIdx.x * 256 + threadIdx.x;   // 0..524287
  const int i = gi & 262143;
  const bool second = gi >= 262144;
  const float* S1 = second ? W1n : Wgf1;
  const float* S2 = second ? W2n : Wgf2;
  u16* D1 = second ? W1tn : W1t;
  u16* D2 = second ? W2cn : W2c;
  int n1 = i & 1023, k1 = i >> 10;
  int c1 = ((k1 >> 3) ^ (n1 & 31)) & 31;
  D1[n1 * 256 + c1 * 8 + (k1 & 7)] = f2b(S1[k1 * DFF + n1]);
  int n2 = i & 255, k2 = i >> 8;
  int nc = k2 >> 6, kc = k2 & 63;
  int c2 = ((kc >> 3) ^ (n2 & 7)) & 7;
  D2[nc * 16384 + n2 * 64 + c2 * 8 + (kc & 7)] = f2b(S2[k2 * DD + n2]);
}

// ---------------- K1/K3a: three fused 256x256 projections ----------------
__global__ __launch_bounds__(256) void k_proj3(
    const float* __restrict__ in,
    const float* __restrict__ W0, const float* __restrict__ c0,
    const float* __restrict__ W1, const float* __restrict__ c1,
    const float* __restrict__ W2, const float* __restrict__ c2,
    float* __restrict__ o0, float* __restrict__ o1, float* __restrict__ o2) {
  __shared__ float row[DD];
  const int t = threadIdx.x; const int r = blockIdx.x;
  row[t] = in[r * DD + t];
  __syncthreads();
  float a0 = c0[t], a1 = c1[t], a2 = c2[t];
  for (int c = 0; c < DD; ++c) {
    float xv = row[c];
    a0 += xv * W0[c * DD + t];
    a1 += xv * W1[c * DD + t];
    a2 += xv * W2[c * DD + t];
  }
  o0[r * DD + t] = a0; o1[r * DD + t] = a1; o2[r * DD + t] = a2;
}

// ---------------- K2: fused relation attention (unchanged) ----------------
__global__ __launch_bounds__(256) void k2_attn(
    const float* __restrict__ bg, const float* __restrict__ qg,
    const float* __restrict__ kg, const float* __restrict__ vg,
    const float* __restrict__ Wrk, const float* __restrict__ brk,
    const float* __restrict__ Wrv, const float* __restrict__ brv,
    float* __restrict__ attn) {
  extern __shared__ char smem[];
  u16* bgt = (u16*)smem;                     // [128][260]
  float* qs = (float*)(smem + 66560);
  float* U  = (float*)(smem + 67584);
  float* sc = (float*)(smem + 75776);
  float* cb = (float*)(smem + 79872);
  const int t = threadIdx.x;
  const int blk = blockIdx.x;
  const int b = blk >> 7;
  const float* bgbase = bg + (long)blk * (NN * DD);

  qs[t] = qg[blk * DD + t];
  if (t < 8) {
    float s = 0.f;
    #pragma unroll
    for (int d = 0; d < 32; ++d) s += brk[t * 32 + d] * qg[blk * DD + t * 32 + d];
    cb[t] = s;
  }
  for (int i = 0; i < 32; ++i) {
    int e4 = i * 256 + t;
    float4 vv = *(const float4*)(bgbase + (long)e4 * 4);
    int e = e4 * 4; int row = e >> 8, col = e & 255;
    u32 p0 = (u32)f2b(vv.x) | ((u32)f2b(vv.y) << 16);
    u32 p1 = (u32)f2b(vv.z) | ((u32)f2b(vv.w) << 16);
    *(u32*)(bgt + row * 260 + col) = p0;
    *(u32*)(bgt + row * 260 + col + 2) = p1;
  }
  __syncthreads();
  {
    const float* wr = Wrk + t * DD;
    #pragma unroll
    for (int h = 0; h < 8; ++h) {
      float s = 0.f;
      #pragma unroll
      for (int d = 0; d < 32; ++d) s += wr[h * 32 + d] * qs[h * 32 + d];
      U[t * 8 + h] = s;
    }
  }
  __syncthreads();
  {
    const int h = t & 7, y0 = t >> 3;
    #pragma unroll
    for (int yy = 0; yy < 4; ++yy) {
      int y = y0 + yy * 32;
      float s = cb[h];
      const float* kr = kg + (long)(b * NN + y) * DD + h * 32;
      const float* qh = qs + h * 32;
      #pragma unroll
      for (int d = 0; d < 32; ++d) s += qh[d] * kr[d];
      const u16* br = bgt + y * 260;
      for (int c = 0; c < 256; c += 2) {
        u32 pk = *(const u32*)(br + c);
        s += b2f((u16)pk) * U[c * 8 + h] + b2f((u16)(pk >> 16)) * U[(c + 1) * 8 + h];
      }
      sc[y * 8 + h] = s * 0.1767766952966369f;
    }
  }
  __syncthreads();
  {
    const int h = t >> 5, ln = t & 31;
    float v0 = sc[ln * 8 + h], v1 = sc[(ln + 32) * 8 + h];
    float v2 = sc[(ln + 64) * 8 + h], v3 = sc[(ln + 96) * 8 + h];
    float mx = fmaxf(fmaxf(v0, v1), fmaxf(v2, v3));
    #pragma unroll
    for (int m = 1; m < 32; m <<= 1) mx = fmaxf(mx, __shfl_xor(mx, m, 32));
    float e0 = __expf(v0 - mx), e1 = __expf(v1 - mx);
    float e2 = __expf(v2 - mx), e3 = __expf(v3 - mx);
    float sm = e0 + e1 + e2 + e3;
    #pragma unroll
    for (int m = 1; m < 32; m <<= 1) sm += __shfl_xor(sm, m, 32);
    float inv = 1.f / sm;
    sc[ln * 8 + h] = e0 * inv; sc[(ln + 32) * 8 + h] = e1 * inv;
    sc[(ln + 64) * 8 + h] = e2 * inv; sc[(ln + 96) * 8 + h] = e3 * inv;
  }
  __syncthreads();
  {
    float acc[8];
    #pragma unroll
    for (int h = 0; h < 8; ++h) acc[h] = 0.f;
    for (int y = 0; y < 128; ++y) {
      float bv = b2f(bgt[y * 260 + t]);
      const float* pr = sc + y * 8;
      #pragma unroll
      for (int h = 0; h < 8; ++h) acc[h] += pr[h] * bv;
    }
    #pragma unroll
    for (int h = 0; h < 8; ++h) U[t * 8 + h] = acc[h];
  }
  __syncthreads();
  {
    const int h = t >> 5;
    float av = 0.f;
    for (int y = 0; y < 128; ++y) av += sc[y * 8 + h] * vg[(long)(b * NN + y) * DD + t];
    float ag = 0.f;
    for (int c = 0; c < 256; ++c) ag += U[c * 8 + h] * Wrv[c * DD + t];
    attn[blk * DD + t] = av + ag + brv[t];
  }
}

// ---------------- K4 v8: merged graph+node FFN; PROBE=1 -> no-stage ablation ----
// grid 512 (blocks 0..3 run 2 tiles: graph then node) -> 2 clean rounds.
// PROBE: grid 1536, graph tiles only, stages REMOVED, output to masked scratch.
template<int PROBE>
__global__ __launch_bounds__(512, 2) void k4_kern(
    const float* __restrict__ bg, const float* __restrict__ aL, const float* __restrict__ aR,
    const u16* __restrict__ W1t, const float* __restrict__ bgf1,
    const u16* __restrict__ W2c, const float* __restrict__ bgf2,
    const float* __restrict__ gg1, const float* __restrict__ betag1,
    const float* __restrict__ gg2, const float* __restrict__ betag2,
    float* __restrict__ outbg,
    const float* __restrict__ x, const float* __restrict__ x2,
    const u16* __restrict__ W1tn, const float* __restrict__ b1n,
    const u16* __restrict__ W2cn, const float* __restrict__ b2n,
    const float* __restrict__ g1n, const float* __restrict__ beta1n,
    const float* __restrict__ g2n, const float* __restrict__ beta2n,
    float* __restrict__ outx) {
  extern __shared__ char ldsc[];
  u16* As = (u16*)ldsc;              // [128][256] (phase0 + epilogue)
  u16* Ff = (u16*)(ldsc + 131072);   // [128][64]
  const int t = threadIdx.x;
  const int bid = blockIdx.x;
  const int l = t & 63, w = t >> 6, lm = l & 31, hl = l >> 5;
  const int wm = w & 3, wn = w >> 2;
  const int bl = wn * 32 + lm;
  const int frow = wm * 32 + lm;
  const int arow = wm * 32 + lm;

  const int ntile = (!PROBE && bid < 4) ? 2 : 1;
  for (int ti = 0; ti < ntile; ++ti) {
    const bool node = (!PROBE) && (ti == 1);
    const int gb = PROBE ? (bid & 511) : bid;
    const int blk = node ? bid : (((gb & 7) << 6) | (gb >> 3));
    const long r0 = (long)blk * 128;

    const u16* W1sel = node ? W1tn : W1t;
    const u16* W2sel = node ? W2cn : W2c;
    const float* bi1 = node ? b1n : bgf1;
    const float* bi2 = node ? b2n : bgf2;
    const float* ga1 = node ? g1n : gg1;
    const float* bt1 = node ? beta1n : betag1;
    const float* ga2 = node ? g2n : gg2;
    const float* bt2 = node ? beta2n : betag2;
    float* outp = node ? outx : outbg;

    // ---- Phase 0: As = bf16(LN(residual sum)); 4 lanes/row, 128 rows
    {
      const int row = t >> 2, sub = t & 3;
      const long r = r0 + row;
      const int bx = (int)(r >> 7);
      const int by = (int)(((r >> 14) << 7) | (r & 127));
      const float4* pb = (const float4*)((node ? x : bg) + r * 256 + sub * 64);
      const float4* pl = node ? (const float4*)(x2 + r * 256 + sub * 64)
                              : (const float4*)(aL + (long)bx * 256 + sub * 64);
      const float4* pr = (const float4*)(aR + (long)(node ? 0 : by) * 256 + sub * 64);
      const float s3 = node ? 0.f : 1.f;
      float v[64];
      float s = 0.f, sq = 0.f;
      #pragma unroll
      for (int i = 0; i < 16; ++i) {
        float4 a = pb[i], b = pl[i], c = pr[i];
        float x0 = a.x + b.x + s3 * c.x, x1 = a.y + b.y + s3 * c.y;
        float x2v = a.z + b.z + s3 * c.z, x3 = a.w + b.w + s3 * c.w;
        v[4 * i] = x0; v[4 * i + 1] = x1; v[4 * i + 2] = x2v; v[4 * i + 3] = x3;
        s += x0 + x1 + x2v + x3;
        sq += x0 * x0 + x1 * x1 + x2v * x2v + x3 * x3;
      }
      s += __shfl_xor(s, 1); s += __shfl_xor(s, 2);
      sq += __shfl_xor(sq, 1); sq += __shfl_xor(sq, 2);
      float mean = s * (1.f / 256.f);
      float var = sq * (1.f / 256.f) - mean * mean;
      float rsd = rsqrtf(var + 1e-5f);
      const float* g = ga1 + sub * 64; const float* be = bt1 + sub * 64;
      #pragma unroll
      for (int j8 = 0; j8 < 8; ++j8) {
        short8 pk;
        #pragma unroll
        for (int e = 0; e < 8; ++e) {
          int j = j8 * 8 + e;
          pk[e] = (short)f2b((v[j] - mean) * rsd * g[j] + be[j]);
        }
        int c = (sub * 8 + j8) ^ (row & 31);
        *(short8*)(As + row * 256 + c * 8) = pk;
      }
    }
    __syncthreads();

    // ---- A fragments into registers
    short8 a[16];
    #pragma unroll
    for (int kk = 0; kk < 16; ++kk)
      a[kk] = *(const short8*)(As + arow * 256 + ((kk * 2 + hl) ^ lm) * 8);
    __syncthreads();

  #define STAGE_B1(c_) if (!PROBE) { const char* s_ = (const char*)W1sel + (size_t)(c_) * 32768; \
    char* d_ = ldsc + ((c_) & 1) * 32768; \
    _Pragma("unroll") for (int j_ = 0; j_ < 4; ++j_) { int p_ = j_ * 8192 + t * 16; \
      gld_lds16(s_ + p_, d_ + p_); } }
  #define STAGE_B2(c_) if (!PROBE) { const char* s_ = (const char*)W2sel + (size_t)(c_) * 32768; \
    char* d_ = ldsc + 65536 + ((c_) & 1) * 32768; \
    _Pragma("unroll") for (int j_ = 0; j_ < 4; ++j_) { int p_ = j_ * 8192 + t * 16; \
      gld_lds16(s_ + p_, d_ + p_); } }

    f32x16 acc2[4];
    #pragma unroll
    for (int i = 0; i < 4; ++i)
      #pragma unroll
      for (int r = 0; r < 16; ++r) acc2[i][r] = 0.f;

    STAGE_B1(0);

    for (int nc = 0; nc <= 16; ++nc) {
      __syncthreads();
      float bias = 0.f;
      if (nc < 16) bias = bi1[nc * 64 + bl];
      if (nc < 15) STAGE_B1(nc + 1);
      if (nc < 16) STAGE_B2(nc);
      f32x16 acc1;
      if (nc < 16) {
        const u16* B1cur = (const u16*)(ldsc + (nc & 1) * 32768);
        #pragma unroll
        for (int r = 0; r < 16; ++r) acc1[r] = 0.f;
        #pragma unroll
        for (int kk = 0; kk < 16; ++kk) {
          short8 bf = *(const short8*)(B1cur + bl * 256 + ((kk * 2 + hl) ^ lm) * 8);
          acc1 = __builtin_amdgcn_mfma_f32_32x32x16_bf16(a[kk], bf, acc1, 0, 0, 0);
        }
      }
      if (nc > 0) {
        const u16* B2cur = (const u16*)(ldsc + 65536 + ((nc - 1) & 1) * 32768);
        short8 af[4];
        #pragma unroll
        for (int ks = 0; ks < 4; ++ks)
          af[ks] = *(const short8*)(Ff + frow * 64 + (((ks * 2 + hl) ^ (lm & 7)) * 8));
        #pragma unroll
        for (int nt = 0; nt < 4; ++nt) {
          int n = wn * 128 + nt * 32 + lm;
          #pragma unroll
          for (int ks = 0; ks < 4; ++ks) {
            short8 bf = *(const short8*)(B2cur + n * 64 + (((ks * 2 + hl) ^ (lm & 7)) * 8));
            acc2[nt] = __builtin_amdgcn_mfma_f32_32x32x16_bf16(af[ks], bf, acc2[nt], 0, 0, 0);
          }
        }
      }
      if (nc < 16) {
        asm volatile("s_waitcnt lgkmcnt(0)" ::: "memory");
        __builtin_amdgcn_sched_barrier(0);
        __builtin_amdgcn_s_barrier();
        #pragma unroll
        for (int r = 0; r < 16; ++r) {
          int row = wm * 32 + (r & 3) + 8 * (r >> 2) + 4 * hl;
          Ff[row * 64 + ((bl >> 3) ^ (row & 7)) * 8 + (bl & 7)] = f2b(fmaxf(acc1[r] + bias, 0.f));
        }
      }
    }
    __syncthreads();

    // ---- Epilogue
    if (wn == 0) {
      #pragma unroll
      for (int kk = 0; kk < 16; ++kk)
        *(short8*)(As + arow * 256 + ((kk * 2 + hl) ^ lm) * 8) = a[kk];
    }
    __syncthreads();

    float gv[4], bev[4], bf2v[4];
    #pragma unroll
    for (int nt = 0; nt < 4; ++nt) {
      int col = wn * 128 + nt * 32 + lm;
      gv[nt] = ga2[col]; bev[nt] = bt2[col]; bf2v[nt] = bi2[col];
    }
    #pragma unroll
    for (int nt = 0; nt < 4; ++nt) {
      int col = wn * 128 + nt * 32 + lm;
      #pragma unroll
      for (int r = 0; r < 16; ++r) {
        int row = wm * 32 + (r & 3) + 8 * (r >> 2) + 4 * hl;
        float res = b2f(As[row * 256 + ((col >> 3) ^ (row & 31)) * 8 + (col & 7)]);
        acc2[nt][r] += bf2v[nt] + res;
      }
    }
    __syncthreads();

    float* red_s = (float*)Ff;
    float* red_q = red_s + 256;
    float* mrs   = red_q + 256;
    #pragma unroll
    for (int r = 0; r < 16; ++r) {
      int row = wm * 32 + (r & 3) + 8 * (r >> 2) + 4 * hl;
      float s = acc2[0][r] + acc2[1][r] + acc2[2][r] + acc2[3][r];
      float q = acc2[0][r] * acc2[0][r] + acc2[1][r] * acc2[1][r]
              + acc2[2][r] * acc2[2][r] + acc2[3][r] * acc2[3][r];
      #pragma unroll
      for (int m = 1; m < 32; m <<= 1) { s += __shfl_xor(s, m, 32); q += __shfl_xor(q, m, 32); }
      if (lm == 0) { red_s[wn * 128 + row] = s; red_q[wn * 128 + row] = q; }
    }
    __syncthreads();
    if (t < 128) {
      float s = red_s[t] + red_s[128 + t];
      float q = red_q[t] + red_q[128 + t];
      float mean = s * (1.f / 256.f);
      float var = q * (1.f / 256.f) - mean * mean;
      mrs[2 * t] = mean; mrs[2 * t + 1] = rsqrtf(var + 1e-5f);
    }
    __syncthreads();
    #pragma unroll
    for (int nt = 0; nt < 4; ++nt) {
      int col = wn * 128 + nt * 32 + lm;
      #pragma unroll
      for (int r = 0; r < 16; ++r) {
        int row = wm * 32 + (r & 3) + 8 * (r >> 2) + 4 * hl;
        float mean = mrs[2 * row], rstd = mrs[2 * row + 1];
        long orow = PROBE ? ((long)(blk & 3) * 128 + row) : (r0 + row);
        outp[orow * 256 + col] = (acc2[nt][r] - mean) * rstd * gv[nt] + bev[nt];
      }
    }
    __syncthreads();   // tile boundary: all LDS reads done before next phase0
  }
  #undef STAGE_B1
  #undef STAGE_B2
}

// ---------------- host ----------------
extern "C" void kernel_launch(void* const* d_in, const int* in_sizes, int n_in,
                              void* d_out, int out_size, void* d_ws, size_t ws_size,
                              hipStream_t stream) {
  const float* x      = (const float*)d_in[0];
  const float* bg     = (const float*)d_in[1];
  const float* Wq     = (const float*)d_in[3];  const float* bq     = (const float*)d_in[4];
  const float* Wk     = (const float*)d_in[5];  const float* bk     = (const float*)d_in[6];
  const float* Wv     = (const float*)d_in[7];  const float* bv     = (const float*)d_in[8];
  const float* Wo     = (const float*)d_in[9];  const float* bo     = (const float*)d_in[10];
  const float* Wleft  = (const float*)d_in[11]; const float* bleft  = (const float*)d_in[12];
  const float* Wright = (const float*)d_in[13]; const float* bright = (const float*)d_in[14];
  const float* Wrk    = (const float*)d_in[15]; const float* brk    = (const float*)d_in[16];
  const float* Wrv    = (const float*)d_in[17]; const float* brv    = (const float*)d_in[18];
  const float* W1     = (const float*)d_in[19]; const float* b1     = (const float*)d_in[20];
  const float* W2     = (const float*)d_in[21]; const float* b2     = (const float*)d_in[22];
  const float* Wgf1   = (const float*)d_in[23]; const float* bgf1   = (const float*)d_in[24];
  const float* Wgf2   = (const float*)d_in[25]; const float* bgf2   = (const float*)d_in[26];
  const float* g1     = (const float*)d_in[27]; const float* g2     = (const float*)d_in[28];
  const float* gg1    = (const float*)d_in[29]; const float* gg2    = (const float*)d_in[30];
  const float* beta1  = (const float*)d_in[31]; const float* beta2  = (const float*)d_in[32];
  const float* betag1 = (const float*)d_in[33]; const float* betag2 = (const float*)d_in[34];

  float* ws   = (float*)d_ws;
  float* q    = ws;
  float* k    = ws + 131072;
  float* v    = ws + 262144;
  float* attn = ws + 393216;
  float* x2   = ws + 524288;
  float* aL   = ws + 655360;
  float* aR   = ws + 786432;
  u16* W1t  = (u16*)(ws + 917504);
  u16* W2c  = W1t + 262144;
  u16* W1tn = W2c + 262144;
  u16* W2cn = W1tn + 262144;
  float* probeOut = ws + 1441792;   // 4 tiles x 128 x 256 = 512KB scratch

  float* outx  = (float*)d_out;
  float* outbg = outx + 131072;

  hipFuncSetAttribute((const void*)k2_attn, hipFuncAttributeMaxDynamicSharedMemorySize, 79904);
  hipFuncSetAttribute((const void*)k4_kern<0>, hipFuncAttributeMaxDynamicSharedMemorySize, 147456);
  hipFuncSetAttribute((const void*)k4_kern<1>, hipFuncAttributeMaxDynamicSharedMemorySize, 147456);

  k0_conv <<<2048, 256, 0, stream>>>(Wgf1, Wgf2, W1, W2, W1t, W2c, W1tn, W2cn);
  k_proj3 <<<512, 256, 0, stream>>>(x, Wq, bq, Wk, bk, Wv, bv, q, k, v);
  k2_attn <<<512, 256, 79904, stream>>>(bg, q, k, v, Wrk, brk, Wrv, brv, attn);
  k_proj3 <<<512, 256, 0, stream>>>(attn, Wo, bo, Wleft, bleft, Wright, bright, x2, aL, aR);
  k4_kern<0><<<512, 512, 147456, stream>>>(bg, aL, aR, W1t, bgf1, W2c, bgf2,
                                           gg1, betag1, gg2, betag2, outbg,
                                           x, x2, W1tn, b1, W2cn, b2,
                                           g1, beta1, g2, beta2, outx);
  // ---- diagnostic ablation: identical kernel minus global_load_lds stages ----
  k4_kern<1><<<1536, 512, 147456, stream>>>(bg, aL, aR, W1t, bgf1, W2c, bgf2,
                                            gg1, betag1, gg2, betag2, probeOut,
                                            x, x2, W1tn, b1, W2cn, b2,
                                            g1, beta1, g2, beta2, probeOut);
}

// Round 10
// 653.132 us; speedup vs baseline: 1.0697x; 1.0697x over previous
//
#include <hip/hip_runtime.h>

typedef unsigned short u16;
typedef unsigned int u32;
typedef __attribute__((ext_vector_type(8))) short short8;
typedef __attribute__((ext_vector_type(16))) float f32x16;

#define BB 4
#define NN 128
#define DD 256
#define DFF 1024

__device__ __forceinline__ u16 f2b(float f) {
  union { float f; u32 u; } c; c.f = f;
  u32 x = c.u;
  return (u16)((x + 0x7FFFu + ((x >> 16) & 1u)) >> 16);
}
__device__ __forceinline__ float b2f(u16 u) {
  union { u32 u; float f; } c; c.u = ((u32)u) << 16;
  return c.f;
}

__device__ __forceinline__ void gld_lds16(const void* g, void* l) {
  __builtin_amdgcn_global_load_lds(
      (const __attribute__((address_space(1))) unsigned int*)g,
      (__attribute__((address_space(3))) unsigned int*)l, 16, 0, 0);
}

// ---------------- K0: transpose+convert FFN weights (graph AND node) to bf16 ----
// W1t/W1tn: [n][256] pre-swizzled: k-chunk c=(k>>3)^(n&31) at c*8+(k&7).
// W2H/W2Hn: [nc][half][256 n][32 k] LINEAR (no swizzle; 64B row stride = 2-way free).
__global__ void k0_conv(const float* __restrict__ Wgf1, const float* __restrict__ Wgf2,
                        const float* __restrict__ W1n, const float* __restrict__ W2n,
                        u16* __restrict__ W1t, u16* __restrict__ W2H,
                        u16* __restrict__ W1tn, u16* __restrict__ W2Hn) {
  int gi = blockIdx.x * 256 + threadIdx.x;   // 0..524287
  const int i = gi & 262143;
  const bool second = gi >= 262144;
  const float* S1 = second ? W1n : Wgf1;
  const float* S2 = second ? W2n : Wgf2;
  u16* D1 = second ? W1tn : W1t;
  u16* D2 = second ? W2Hn : W2H;
  int n1 = i & 1023, k1 = i >> 10;
  int c1 = ((k1 >> 3) ^ (n1 & 31)) & 31;
  D1[n1 * 256 + c1 * 8 + (k1 & 7)] = f2b(S1[k1 * DFF + n1]);
  int n2 = i & 255, k2 = i >> 8;
  int nc = k2 >> 6, kc = k2 & 63;
  int h = kc >> 5, kh = kc & 31;
  D2[nc * 16384 + h * 8192 + n2 * 32 + kh] = f2b(S2[k2 * DD + n2]);
}

// ---------------- K1/K3a: three fused 256x256 projections ----------------
__global__ __launch_bounds__(256) void k_proj3(
    const float* __restrict__ in,
    const float* __restrict__ W0, const float* __restrict__ c0,
    const float* __restrict__ W1, const float* __restrict__ c1,
    const float* __restrict__ W2, const float* __restrict__ c2,
    float* __restrict__ o0, float* __restrict__ o1, float* __restrict__ o2) {
  __shared__ float row[DD];
  const int t = threadIdx.x; const int r = blockIdx.x;
  row[t] = in[r * DD + t];
  __syncthreads();
  float a0 = c0[t], a1 = c1[t], a2 = c2[t];
  for (int c = 0; c < DD; ++c) {
    float xv = row[c];
    a0 += xv * W0[c * DD + t];
    a1 += xv * W1[c * DD + t];
    a2 += xv * W2[c * DD + t];
  }
  o0[r * DD + t] = a0; o1[r * DD + t] = a1; o2[r * DD + t] = a2;
}

// ---------------- K2: fused relation attention (unchanged) ----------------
__global__ __launch_bounds__(256) void k2_attn(
    const float* __restrict__ bg, const float* __restrict__ qg,
    const float* __restrict__ kg, const float* __restrict__ vg,
    const float* __restrict__ Wrk, const float* __restrict__ brk,
    const float* __restrict__ Wrv, const float* __restrict__ brv,
    float* __restrict__ attn) {
  extern __shared__ char smem[];
  u16* bgt = (u16*)smem;                     // [128][260]
  float* qs = (float*)(smem + 66560);
  float* U  = (float*)(smem + 67584);
  float* sc = (float*)(smem + 75776);
  float* cb = (float*)(smem + 79872);
  const int t = threadIdx.x;
  const int blk = blockIdx.x;
  const int b = blk >> 7;
  const float* bgbase = bg + (long)blk * (NN * DD);

  qs[t] = qg[blk * DD + t];
  if (t < 8) {
    float s = 0.f;
    #pragma unroll
    for (int d = 0; d < 32; ++d) s += brk[t * 32 + d] * qg[blk * DD + t * 32 + d];
    cb[t] = s;
  }
  for (int i = 0; i < 32; ++i) {
    int e4 = i * 256 + t;
    float4 vv = *(const float4*)(bgbase + (long)e4 * 4);
    int e = e4 * 4; int row = e >> 8, col = e & 255;
    u32 p0 = (u32)f2b(vv.x) | ((u32)f2b(vv.y) << 16);
    u32 p1 = (u32)f2b(vv.z) | ((u32)f2b(vv.w) << 16);
    *(u32*)(bgt + row * 260 + col) = p0;
    *(u32*)(bgt + row * 260 + col + 2) = p1;
  }
  __syncthreads();
  {
    const float* wr = Wrk + t * DD;
    #pragma unroll
    for (int h = 0; h < 8; ++h) {
      float s = 0.f;
      #pragma unroll
      for (int d = 0; d < 32; ++d) s += wr[h * 32 + d] * qs[h * 32 + d];
      U[t * 8 + h] = s;
    }
  }
  __syncthreads();
  {
    const int h = t & 7, y0 = t >> 3;
    #pragma unroll
    for (int yy = 0; yy < 4; ++yy) {
      int y = y0 + yy * 32;
      float s = cb[h];
      const float* kr = kg + (long)(b * NN + y) * DD + h * 32;
      const float* qh = qs + h * 32;
      #pragma unroll
      for (int d = 0; d < 32; ++d) s += qh[d] * kr[d];
      const u16* br = bgt + y * 260;
      for (int c = 0; c < 256; c += 2) {
        u32 pk = *(const u32*)(br + c);
        s += b2f((u16)pk) * U[c * 8 + h] + b2f((u16)(pk >> 16)) * U[(c + 1) * 8 + h];
      }
      sc[y * 8 + h] = s * 0.1767766952966369f;
    }
  }
  __syncthreads();
  {
    const int h = t >> 5, ln = t & 31;
    float v0 = sc[ln * 8 + h], v1 = sc[(ln + 32) * 8 + h];
    float v2 = sc[(ln + 64) * 8 + h], v3 = sc[(ln + 96) * 8 + h];
    float mx = fmaxf(fmaxf(v0, v1), fmaxf(v2, v3));
    #pragma unroll
    for (int m = 1; m < 32; m <<= 1) mx = fmaxf(mx, __shfl_xor(mx, m, 32));
    float e0 = __expf(v0 - mx), e1 = __expf(v1 - mx);
    float e2 = __expf(v2 - mx), e3 = __expf(v3 - mx);
    float sm = e0 + e1 + e2 + e3;
    #pragma unroll
    for (int m = 1; m < 32; m <<= 1) sm += __shfl_xor(sm, m, 32);
    float inv = 1.f / sm;
    sc[ln * 8 + h] = e0 * inv; sc[(ln + 32) * 8 + h] = e1 * inv;
    sc[(ln + 64) * 8 + h] = e2 * inv; sc[(ln + 96) * 8 + h] = e3 * inv;
  }
  __syncthreads();
  {
    float acc[8];
    #pragma unroll
    for (int h = 0; h < 8; ++h) acc[h] = 0.f;
    for (int y = 0; y < 128; ++y) {
      float bv = b2f(bgt[y * 260 + t]);
      const float* pr = sc + y * 8;
      #pragma unroll
      for (int h = 0; h < 8; ++h) acc[h] += pr[h] * bv;
    }
    #pragma unroll
    for (int h = 0; h < 8; ++h) U[t * 8 + h] = acc[h];
  }
  __syncthreads();
  {
    const int h = t >> 5;
    float av = 0.f;
    for (int y = 0; y < 128; ++y) av += sc[y * 8 + h] * vg[(long)(b * NN + y) * DD + t];
    float ag = 0.f;
    for (int c = 0; c < 256; ++c) ag += U[c * 8 + h] * Wrv[c * DD + t];
    attn[blk * DD + t] = av + ag + brv[t];
  }
}

// ---------------- K4 v9: 66KB LDS -> 2 blocks/CU; single-buf B1 + half-staged B2 ----
// 512 blocks x 512 thr (4M x 2N waves); blocks 0..3 run a second (node) tile.
// LDS 67584B: B1s[64][256] @0 (32K, swz), B2h[256][32] @32768 (16K, linear),
//             Ff[128][72] @49152 (18K, pad-72 -> 4-way max).  As[128][256] overlays 0..64K.
__global__ __launch_bounds__(512, 4) void k4_kern(
    const float* __restrict__ bg, const float* __restrict__ aL, const float* __restrict__ aR,
    const u16* __restrict__ W1t, const float* __restrict__ bgf1,
    const u16* __restrict__ W2H, const float* __restrict__ bgf2,
    const float* __restrict__ gg1, const float* __restrict__ betag1,
    const float* __restrict__ gg2, const float* __restrict__ betag2,
    float* __restrict__ outbg,
    const float* __restrict__ x, const float* __restrict__ x2,
    const u16* __restrict__ W1tn, const float* __restrict__ b1n,
    const u16* __restrict__ W2Hn, const float* __restrict__ b2n,
    const float* __restrict__ g1n, const float* __restrict__ beta1n,
    const float* __restrict__ g2n, const float* __restrict__ beta2n,
    float* __restrict__ outx) {
  extern __shared__ char ldsc[];
  u16* As  = (u16*)ldsc;              // [128][256] (phase0 + epilogue)
  u16* B1s = (u16*)ldsc;              // [64][256] swizzled
  u16* B2h = (u16*)(ldsc + 32768);    // [256][32] linear half
  u16* Ff  = (u16*)(ldsc + 49152);    // [128][72] padded
  const int t = threadIdx.x;
  const int bid = blockIdx.x;
  const int l = t & 63, w = t >> 6, lm = l & 31, hl = l >> 5;
  const int wm = w & 3, wn = w >> 2;
  const int bl = wn * 32 + lm;
  const int frow = wm * 32 + lm;
  const int arow = wm * 32 + lm;

  const int ntile = (bid < 4) ? 2 : 1;
  for (int ti = 0; ti < ntile; ++ti) {
    const bool node = (ti == 1);
    const int blk = node ? bid : (((bid & 7) << 6) | (bid >> 3));
    const long r0 = (long)blk * 128;

    const u16* W1sel = node ? W1tn : W1t;
    const u16* W2sel = node ? W2Hn : W2H;
    const float* bi1 = node ? b1n : bgf1;
    const float* bi2 = node ? b2n : bgf2;
    const float* ga1 = node ? g1n : gg1;
    const float* bt1 = node ? beta1n : betag1;
    const float* ga2 = node ? g2n : gg2;
    const float* bt2 = node ? beta2n : betag2;
    float* outp = node ? outx : outbg;

    // ---- Phase 0: As = bf16(LN(residual sum)); 4 lanes/row, 128 rows
    {
      const int row = t >> 2, sub = t & 3;
      const long r = r0 + row;
      const int bx = (int)(r >> 7);
      const int by = (int)(((r >> 14) << 7) | (r & 127));
      const float4* pb = (const float4*)((node ? x : bg) + r * 256 + sub * 64);
      const float4* pl = node ? (const float4*)(x2 + r * 256 + sub * 64)
                              : (const float4*)(aL + (long)bx * 256 + sub * 64);
      const float4* pr = (const float4*)(aR + (long)(node ? 0 : by) * 256 + sub * 64);
      const float s3 = node ? 0.f : 1.f;
      float v[64];
      float s = 0.f, sq = 0.f;
      #pragma unroll
      for (int i = 0; i < 16; ++i) {
        float4 a = pb[i], b = pl[i], c = pr[i];
        float x0 = a.x + b.x + s3 * c.x, x1 = a.y + b.y + s3 * c.y;
        float x2v = a.z + b.z + s3 * c.z, x3 = a.w + b.w + s3 * c.w;
        v[4 * i] = x0; v[4 * i + 1] = x1; v[4 * i + 2] = x2v; v[4 * i + 3] = x3;
        s += x0 + x1 + x2v + x3;
        sq += x0 * x0 + x1 * x1 + x2v * x2v + x3 * x3;
      }
      s += __shfl_xor(s, 1); s += __shfl_xor(s, 2);
      sq += __shfl_xor(sq, 1); sq += __shfl_xor(sq, 2);
      float mean = s * (1.f / 256.f);
      float var = sq * (1.f / 256.f) - mean * mean;
      float rsd = rsqrtf(var + 1e-5f);
      const float* g = ga1 + sub * 64; const float* be = bt1 + sub * 64;
      #pragma unroll
      for (int j8 = 0; j8 < 8; ++j8) {
        short8 pk;
        #pragma unroll
        for (int e = 0; e < 8; ++e) {
          int j = j8 * 8 + e;
          pk[e] = (short)f2b((v[j] - mean) * rsd * g[j] + be[j]);
        }
        int c = (sub * 8 + j8) ^ (row & 31);
        *(short8*)(As + row * 256 + c * 8) = pk;
      }
    }
    __syncthreads();

    // ---- A fragments into registers
    short8 a[16];
    #pragma unroll
    for (int kk = 0; kk < 16; ++kk)
      a[kk] = *(const short8*)(As + arow * 256 + ((kk * 2 + hl) ^ lm) * 8);
    __syncthreads();   // a-loads done; As region reusable for stages

  #define STAGE_B1(c_) { const char* s_ = (const char*)W1sel + (size_t)(c_) * 32768; \
    _Pragma("unroll") for (int j_ = 0; j_ < 4; ++j_) { int p_ = j_ * 8192 + t * 16; \
      gld_lds16(s_ + p_, ldsc + p_); } }
  #define STAGE_B2H(c_, h_) { const char* s_ = (const char*)W2sel + (size_t)(c_) * 32768 + (h_) * 16384; \
    _Pragma("unroll") for (int j_ = 0; j_ < 2; ++j_) { int p_ = j_ * 8192 + t * 16; \
      gld_lds16(s_ + p_, ldsc + 32768 + p_); } }

    f32x16 acc2[4];
    #pragma unroll
    for (int i = 0; i < 4; ++i)
      #pragma unroll
      for (int r = 0; r < 16; ++r) acc2[i][r] = 0.f;

    STAGE_B1(0);
    STAGE_B2H(0, 0);

    for (int nc = 0; nc < 16; ++nc) {
      // B1(nc) + B2 half0(nc) visible after drain
      asm volatile("s_waitcnt vmcnt(0)" ::: "memory");
      __builtin_amdgcn_sched_barrier(0);
      __builtin_amdgcn_s_barrier();
      float bias = bi1[nc * 64 + bl];
      // ---- GEMM1(nc)
      f32x16 acc1;
      #pragma unroll
      for (int r = 0; r < 16; ++r) acc1[r] = 0.f;
      #pragma unroll
      for (int kk = 0; kk < 16; ++kk) {
        short8 bf = *(const short8*)(B1s + bl * 256 + ((kk * 2 + hl) ^ lm) * 8);
        acc1 = __builtin_amdgcn_mfma_f32_32x32x16_bf16(a[kk], bf, acc1, 0, 0, 0);
      }
      asm volatile("s_waitcnt lgkmcnt(0)" ::: "memory");
      __builtin_amdgcn_sched_barrier(0);
      __builtin_amdgcn_s_barrier();          // B1s reads done on all waves
      if (nc < 15) STAGE_B1(nc + 1);         // async into B1s, drained next chunk
      // ---- Fwrite(nc)
      #pragma unroll
      for (int r = 0; r < 16; ++r) {
        int row = wm * 32 + (r & 3) + 8 * (r >> 2) + 4 * hl;
        Ff[row * 72 + bl] = f2b(fmaxf(acc1[r] + bias, 0.f));
      }
      asm volatile("s_waitcnt lgkmcnt(0)" ::: "memory");
      __builtin_amdgcn_sched_barrier(0);
      __builtin_amdgcn_s_barrier();          // F visible
      // ---- GEMM2 half 0 (k 0..31 of chunk)
      {
        short8 af[2];
        #pragma unroll
        for (int ksl = 0; ksl < 2; ++ksl)
          af[ksl] = *(const short8*)(Ff + frow * 72 + (ksl * 2 + hl) * 8);
        #pragma unroll
        for (int nt = 0; nt < 4; ++nt) {
          int n = wn * 128 + nt * 32 + lm;
          #pragma unroll
          for (int ksl = 0; ksl < 2; ++ksl) {
            short8 bf = *(const short8*)(B2h + n * 32 + ksl * 16 + hl * 8);
            acc2[nt] = __builtin_amdgcn_mfma_f32_32x32x16_bf16(af[ksl], bf, acc2[nt], 0, 0, 0);
          }
        }
      }
      asm volatile("s_waitcnt lgkmcnt(0)" ::: "memory");
      __builtin_amdgcn_sched_barrier(0);
      __builtin_amdgcn_s_barrier();          // B2h0 reads done
      STAGE_B2H(nc, 1);
      asm volatile("s_waitcnt vmcnt(0)" ::: "memory");
      __builtin_amdgcn_sched_barrier(0);
      __builtin_amdgcn_s_barrier();          // B2h1 (+B1(nc+1)) visible
      // ---- GEMM2 half 1 (k 32..63)
      {
        short8 af[2];
        #pragma unroll
        for (int ksl = 0; ksl < 2; ++ksl)
          af[ksl] = *(const short8*)(Ff + frow * 72 + ((2 + ksl) * 2 + hl) * 8);
        #pragma unroll
        for (int nt = 0; nt < 4; ++nt) {
          int n = wn * 128 + nt * 32 + lm;
          #pragma unroll
          for (int ksl = 0; ksl < 2; ++ksl) {
            short8 bf = *(const short8*)(B2h + n * 32 + ksl * 16 + hl * 8);
            acc2[nt] = __builtin_amdgcn_mfma_f32_32x32x16_bf16(af[ksl], bf, acc2[nt], 0, 0, 0);
          }
        }
      }
      asm volatile("s_waitcnt lgkmcnt(0)" ::: "memory");
      __builtin_amdgcn_sched_barrier(0);
      __builtin_amdgcn_s_barrier();          // B2h1 + Ff reads done
      if (nc < 15) STAGE_B2H(nc + 1, 0);     // drained at next chunk head
    }
    __syncthreads();

    // ---- Epilogue: restore normed residual into As, residual + LN
    if (wn == 0) {
      #pragma unroll
      for (int kk = 0; kk < 16; ++kk)
        *(short8*)(As + arow * 256 + ((kk * 2 + hl) ^ lm) * 8) = a[kk];
    }
    __syncthreads();

    float gv[4], bev[4], bf2v[4];
    #pragma unroll
    for (int nt = 0; nt < 4; ++nt) {
      int col = wn * 128 + nt * 32 + lm;
      gv[nt] = ga2[col]; bev[nt] = bt2[col]; bf2v[nt] = bi2[col];
    }
    #pragma unroll
    for (int nt = 0; nt < 4; ++nt) {
      int col = wn * 128 + nt * 32 + lm;
      #pragma unroll
      for (int r = 0; r < 16; ++r) {
        int row = wm * 32 + (r & 3) + 8 * (r >> 2) + 4 * hl;
        float res = b2f(As[row * 256 + ((col >> 3) ^ (row & 31)) * 8 + (col & 7)]);
        acc2[nt][r] += bf2v[nt] + res;
      }
    }
    __syncthreads();   // As reads done before LDS reuse below

    float* red_s = (float*)Ff;          // [2][128]
    float* red_q = red_s + 256;
    float* mrs   = red_q + 256;
    #pragma unroll
    for (int r = 0; r < 16; ++r) {
      int row = wm * 32 + (r & 3) + 8 * (r >> 2) + 4 * hl;
      float s = acc2[0][r] + acc2[1][r] + acc2[2][r] + acc2[3][r];
      float q = acc2[0][r] * acc2[0][r] + acc2[1][r] * acc2[1][r]
              + acc2[2][r] * acc2[2][r] + acc2[3][r] * acc2[3][r];
      #pragma unroll
      for (int m = 1; m < 32; m <<= 1) { s += __shfl_xor(s, m, 32); q += __shfl_xor(q, m, 32); }
      if (lm == 0) { red_s[wn * 128 + row] = s; red_q[wn * 128 + row] = q; }
    }
    __syncthreads();
    if (t < 128) {
      float s = red_s[t] + red_s[128 + t];
      float q = red_q[t] + red_q[128 + t];
      float mean = s * (1.f / 256.f);
      float var = q * (1.f / 256.f) - mean * mean;
      mrs[2 * t] = mean; mrs[2 * t + 1] = rsqrtf(var + 1e-5f);
    }
    __syncthreads();
    #pragma unroll
    for (int nt = 0; nt < 4; ++nt) {
      int col = wn * 128 + nt * 32 + lm;
      #pragma unroll
      for (int r = 0; r < 16; ++r) {
        int row = wm * 32 + (r & 3) + 8 * (r >> 2) + 4 * hl;
        float mean = mrs[2 * row], rstd = mrs[2 * row + 1];
        outp[(r0 + row) * 256 + col] = (acc2[nt][r] - mean) * rstd * gv[nt] + bev[nt];
      }
    }
    __syncthreads();   // tile boundary
  }
  #undef STAGE_B1
  #undef STAGE_B2H
}

// ---------------- host ----------------
extern "C" void kernel_launch(void* const* d_in, const int* in_sizes, int n_in,
                              void* d_out, int out_size, void* d_ws, size_t ws_size,
                              hipStream_t stream) {
  const float* x      = (const float*)d_in[0];
  const float* bg     = (const float*)d_in[1];
  const float* Wq     = (const float*)d_in[3];  const float* bq     = (const float*)d_in[4];
  const float* Wk     = (const float*)d_in[5];  const float* bk     = (const float*)d_in[6];
  const float* Wv     = (const float*)d_in[7];  const float* bv     = (const float*)d_in[8];
  const float* Wo     = (const float*)d_in[9];  const float* bo     = (const float*)d_in[10];
  const float* Wleft  = (const float*)d_in[11]; const float* bleft  = (const float*)d_in[12];
  const float* Wright = (const float*)d_in[13]; const float* bright = (const float*)d_in[14];
  const float* Wrk    = (const float*)d_in[15]; const float* brk    = (const float*)d_in[16];
  const float* Wrv    = (const float*)d_in[17]; const float* brv    = (const float*)d_in[18];
  const float* W1     = (const float*)d_in[19]; const float* b1     = (const float*)d_in[20];
  const float* W2     = (const float*)d_in[21]; const float* b2     = (const float*)d_in[22];
  const float* Wgf1   = (const float*)d_in[23]; const float* bgf1   = (const float*)d_in[24];
  const float* Wgf2   = (const float*)d_in[25]; const float* bgf2   = (const float*)d_in[26];
  const float* g1     = (const float*)d_in[27]; const float* g2     = (const float*)d_in[28];
  const float* gg1    = (const float*)d_in[29]; const float* gg2    = (const float*)d_in[30];
  const float* beta1  = (const float*)d_in[31]; const float* beta2  = (const float*)d_in[32];
  const float* betag1 = (const float*)d_in[33]; const float* betag2 = (const float*)d_in[34];

  float* ws   = (float*)d_ws;
  float* q    = ws;
  float* k    = ws + 131072;
  float* v    = ws + 262144;
  float* attn = ws + 393216;
  float* x2   = ws + 524288;
  float* aL   = ws + 655360;
  float* aR   = ws + 786432;
  u16* W1t  = (u16*)(ws + 917504);
  u16* W2H  = W1t + 262144;
  u16* W1tn = W2H + 262144;
  u16* W2Hn = W1tn + 262144;

  float* outx  = (float*)d_out;
  float* outbg = outx + 131072;

  hipFuncSetAttribute((const void*)k2_attn, hipFuncAttributeMaxDynamicSharedMemorySize, 79904);
  hipFuncSetAttribute((const void*)k4_kern, hipFuncAttributeMaxDynamicSharedMemorySize, 67584);

  k0_conv <<<2048, 256, 0, stream>>>(Wgf1, Wgf2, W1, W2, W1t, W2H, W1tn, W2Hn);
  k_proj3 <<<512, 256, 0, stream>>>(x, Wq, bq, Wk, bk, Wv, bv, q, k, v);
  k2_attn <<<512, 256, 79904, stream>>>(bg, q, k, v, Wrk, brk, Wrv, brv, attn);
  k_proj3 <<<512, 256, 0, stream>>>(attn, Wo, bo, Wleft, bleft, Wright, bright, x2, aL, aR);
  k4_kern <<<512, 512, 67584, stream>>>(bg, aL, aR, W1t, bgf1, W2H, bgf2,
                                        gg1, betag1, gg2, betag2, outbg,
                                        x, x2, W1tn, b1, W2Hn, b2,
                                        g1, beta1, g2, beta2, outx);
}

// Round 11
// 413.064 us; speedup vs baseline: 1.6914x; 1.5812x over previous
//
#include <hip/hip_runtime.h>

typedef unsigned short u16;
typedef unsigned int u32;
typedef __attribute__((ext_vector_type(8))) short short8;
typedef __attribute__((ext_vector_type(16))) float f32x16;

#define BB 4
#define NN 128
#define DD 256
#define DFF 1024

__device__ __forceinline__ u16 f2b(float f) {
  union { float f; u32 u; } c; c.f = f;
  u32 x = c.u;
  return (u16)((x + 0x7FFFu + ((x >> 16) & 1u)) >> 16);
}
__device__ __forceinline__ float b2f(u16 u) {
  union { u32 u; float f; } c; c.u = ((u32)u) << 16;
  return c.f;
}

__device__ __forceinline__ void gld_lds16(const void* g, void* l) {
  __builtin_amdgcn_global_load_lds(
      (const __attribute__((address_space(1))) unsigned int*)g,
      (__attribute__((address_space(3))) unsigned int*)l, 16, 0, 0);
}

// ---------------- K0: transpose+convert FFN weights (graph AND node) to bf16 ----
// W1t/W1tn: [n][256] pre-swizzled: k-chunk c=(k>>3)^(n&31) at c*8+(k&7).
// W2H/W2Hn: [nc][half][pair-row r=n>>1][ci] where ci=((n&1)*4+c)^(r&7), c=k-chunk
//           within half.  Pre-swizzled in GLOBAL so linear gld_lds dest is correct
//           and LDS reads are bank-spread.
__global__ void k0_conv(const float* __restrict__ Wgf1, const float* __restrict__ Wgf2,
                        const float* __restrict__ W1n, const float* __restrict__ W2n,
                        u16* __restrict__ W1t, u16* __restrict__ W2H,
                        u16* __restrict__ W1tn, u16* __restrict__ W2Hn) {
  int gi = blockIdx.x * 256 + threadIdx.x;   // 0..524287
  const int i = gi & 262143;
  const bool second = gi >= 262144;
  const float* S1 = second ? W1n : Wgf1;
  const float* S2 = second ? W2n : Wgf2;
  u16* D1 = second ? W1tn : W1t;
  u16* D2 = second ? W2Hn : W2H;
  int n1 = i & 1023, k1 = i >> 10;
  int c1 = ((k1 >> 3) ^ (n1 & 31)) & 31;
  D1[n1 * 256 + c1 * 8 + (k1 & 7)] = f2b(S1[k1 * DFF + n1]);
  int n2 = i & 255, k2 = i >> 8;
  int nc = k2 >> 6, kc = k2 & 63;
  int h = kc >> 5, kh = kc & 31;
  int c = kh >> 3, e = kh & 7;
  int r = n2 >> 1;
  int ci = (((n2 & 1) << 2) + c) ^ (r & 7);
  D2[nc * 16384 + h * 8192 + r * 64 + ci * 8 + e] = f2b(S2[k2 * DD + n2]);
}

// ---------------- K1/K3a: three fused 256x256 projections ----------------
__global__ __launch_bounds__(256) void k_proj3(
    const float* __restrict__ in,
    const float* __restrict__ W0, const float* __restrict__ c0,
    const float* __restrict__ W1, const float* __restrict__ c1,
    const float* __restrict__ W2, const float* __restrict__ c2,
    float* __restrict__ o0, float* __restrict__ o1, float* __restrict__ o2) {
  __shared__ float row[DD];
  const int t = threadIdx.x; const int r = blockIdx.x;
  row[t] = in[r * DD + t];
  __syncthreads();
  float a0 = c0[t], a1 = c1[t], a2 = c2[t];
  for (int c = 0; c < DD; ++c) {
    float xv = row[c];
    a0 += xv * W0[c * DD + t];
    a1 += xv * W1[c * DD + t];
    a2 += xv * W2[c * DD + t];
  }
  o0[r * DD + t] = a0; o1[r * DD + t] = a1; o2[r * DD + t] = a2;
}

// ---------------- K2: fused relation attention (unchanged) ----------------
__global__ __launch_bounds__(256) void k2_attn(
    const float* __restrict__ bg, const float* __restrict__ qg,
    const float* __restrict__ kg, const float* __restrict__ vg,
    const float* __restrict__ Wrk, const float* __restrict__ brk,
    const float* __restrict__ Wrv, const float* __restrict__ brv,
    float* __restrict__ attn) {
  extern __shared__ char smem[];
  u16* bgt = (u16*)smem;                     // [128][260]
  float* qs = (float*)(smem + 66560);
  float* U  = (float*)(smem + 67584);
  float* sc = (float*)(smem + 75776);
  float* cb = (float*)(smem + 79872);
  const int t = threadIdx.x;
  const int blk = blockIdx.x;
  const int b = blk >> 7;
  const float* bgbase = bg + (long)blk * (NN * DD);

  qs[t] = qg[blk * DD + t];
  if (t < 8) {
    float s = 0.f;
    #pragma unroll
    for (int d = 0; d < 32; ++d) s += brk[t * 32 + d] * qg[blk * DD + t * 32 + d];
    cb[t] = s;
  }
  for (int i = 0; i < 32; ++i) {
    int e4 = i * 256 + t;
    float4 vv = *(const float4*)(bgbase + (long)e4 * 4);
    int e = e4 * 4; int row = e >> 8, col = e & 255;
    u32 p0 = (u32)f2b(vv.x) | ((u32)f2b(vv.y) << 16);
    u32 p1 = (u32)f2b(vv.z) | ((u32)f2b(vv.w) << 16);
    *(u32*)(bgt + row * 260 + col) = p0;
    *(u32*)(bgt + row * 260 + col + 2) = p1;
  }
  __syncthreads();
  {
    const float* wr = Wrk + t * DD;
    #pragma unroll
    for (int h = 0; h < 8; ++h) {
      float s = 0.f;
      #pragma unroll
      for (int d = 0; d < 32; ++d) s += wr[h * 32 + d] * qs[h * 32 + d];
      U[t * 8 + h] = s;
    }
  }
  __syncthreads();
  {
    const int h = t & 7, y0 = t >> 3;
    #pragma unroll
    for (int yy = 0; yy < 4; ++yy) {
      int y = y0 + yy * 32;
      float s = cb[h];
      const float* kr = kg + (long)(b * NN + y) * DD + h * 32;
      const float* qh = qs + h * 32;
      #pragma unroll
      for (int d = 0; d < 32; ++d) s += qh[d] * kr[d];
      const u16* br = bgt + y * 260;
      for (int c = 0; c < 256; c += 2) {
        u32 pk = *(const u32*)(br + c);
        s += b2f((u16)pk) * U[c * 8 + h] + b2f((u16)(pk >> 16)) * U[(c + 1) * 8 + h];
      }
      sc[y * 8 + h] = s * 0.1767766952966369f;
    }
  }
  __syncthreads();
  {
    const int h = t >> 5, ln = t & 31;
    float v0 = sc[ln * 8 + h], v1 = sc[(ln + 32) * 8 + h];
    float v2 = sc[(ln + 64) * 8 + h], v3 = sc[(ln + 96) * 8 + h];
    float mx = fmaxf(fmaxf(v0, v1), fmaxf(v2, v3));
    #pragma unroll
    for (int m = 1; m < 32; m <<= 1) mx = fmaxf(mx, __shfl_xor(mx, m, 32));
    float e0 = __expf(v0 - mx), e1 = __expf(v1 - mx);
    float e2 = __expf(v2 - mx), e3 = __expf(v3 - mx);
    float sm = e0 + e1 + e2 + e3;
    #pragma unroll
    for (int m = 1; m < 32; m <<= 1) sm += __shfl_xor(sm, m, 32);
    float inv = 1.f / sm;
    sc[ln * 8 + h] = e0 * inv; sc[(ln + 32) * 8 + h] = e1 * inv;
    sc[(ln + 64) * 8 + h] = e2 * inv; sc[(ln + 96) * 8 + h] = e3 * inv;
  }
  __syncthreads();
  {
    float acc[8];
    #pragma unroll
    for (int h = 0; h < 8; ++h) acc[h] = 0.f;
    for (int y = 0; y < 128; ++y) {
      float bv = b2f(bgt[y * 260 + t]);
      const float* pr = sc + y * 8;
      #pragma unroll
      for (int h = 0; h < 8; ++h) acc[h] += pr[h] * bv;
    }
    #pragma unroll
    for (int h = 0; h < 8; ++h) U[t * 8 + h] = acc[h];
  }
  __syncthreads();
  {
    const int h = t >> 5;
    float av = 0.f;
    for (int y = 0; y < 128; ++y) av += sc[y * 8 + h] * vg[(long)(b * NN + y) * DD + t];
    float ag = 0.f;
    for (int c = 0; c < 256; ++c) ag += U[c * 8 + h] * Wrv[c * DD + t];
    attn[blk * DD + t] = av + ag + brv[t];
  }
}

// ---------------- K4 v10: 65KB LDS, 2 blocks/CU target; bank-fixed B2/Ff ----------
// 512 blocks x 512 thr (4M x 2N waves); blocks 0..3 run a second (node) tile.
// LDS 66560B: B1s[64][256] @0 (32K, swz), B2h pair-row @32768 (16K, pre-swz),
//             Ff[128][68] @49152 (17408B, pad-68 -> 2-way).  As[128][256] overlays 0..64K.
__global__ __launch_bounds__(512, 2) void k4_kern(
    const float* __restrict__ bg, const float* __restrict__ aL, const float* __restrict__ aR,
    const u16* __restrict__ W1t, const float* __restrict__ bgf1,
    const u16* __restrict__ W2H, const float* __restrict__ bgf2,
    const float* __restrict__ gg1, const float* __restrict__ betag1,
    const float* __restrict__ gg2, const float* __restrict__ betag2,
    float* __restrict__ outbg,
    const float* __restrict__ x, const float* __restrict__ x2,
    const u16* __restrict__ W1tn, const float* __restrict__ b1n,
    const u16* __restrict__ W2Hn, const float* __restrict__ b2n,
    const float* __restrict__ g1n, const float* __restrict__ beta1n,
    const float* __restrict__ g2n, const float* __restrict__ beta2n,
    float* __restrict__ outx) {
  extern __shared__ char ldsc[];
  u16* As  = (u16*)ldsc;              // [128][256] (phase0 + epilogue)
  u16* B1s = (u16*)ldsc;              // [64][256] swizzled
  u16* B2h = (u16*)(ldsc + 32768);    // pair-row swizzled half (16K)
  u16* Ff  = (u16*)(ldsc + 49152);    // [128][68] padded
  const int t = threadIdx.x;
  const int bid = blockIdx.x;
  const int l = t & 63, w = t >> 6, lm = l & 31, hl = l >> 5;
  const int wm = w & 3, wn = w >> 2;
  const int bl = wn * 32 + lm;
  const int frow = wm * 32 + lm;
  const int arow = wm * 32 + lm;

  const int ntile = (bid < 4) ? 2 : 1;
  for (int ti = 0; ti < ntile; ++ti) {
    const bool node = (ti == 1);
    const int blk = node ? bid : (((bid & 7) << 6) | (bid >> 3));
    const long r0 = (long)blk * 128;

    const u16* W1sel = node ? W1tn : W1t;
    const u16* W2sel = node ? W2Hn : W2H;
    const float* bi1 = node ? b1n : bgf1;
    const float* bi2 = node ? b2n : bgf2;
    const float* ga1 = node ? g1n : gg1;
    const float* bt1 = node ? beta1n : betag1;
    const float* ga2 = node ? g2n : gg2;
    const float* bt2 = node ? beta2n : betag2;
    float* outp = node ? outx : outbg;

    // ---- Phase 0: As = bf16(LN(residual sum)); 4 lanes/row, 128 rows
    {
      const int row = t >> 2, sub = t & 3;
      const long r = r0 + row;
      const int bx = (int)(r >> 7);
      const int by = (int)(((r >> 14) << 7) | (r & 127));
      const float4* pb = (const float4*)((node ? x : bg) + r * 256 + sub * 64);
      const float4* pl = node ? (const float4*)(x2 + r * 256 + sub * 64)
                              : (const float4*)(aL + (long)bx * 256 + sub * 64);
      const float4* pr = (const float4*)(aR + (long)(node ? 0 : by) * 256 + sub * 64);
      const float s3 = node ? 0.f : 1.f;
      float v[64];
      float s = 0.f, sq = 0.f;
      #pragma unroll
      for (int i = 0; i < 16; ++i) {
        float4 a = pb[i], b = pl[i], c = pr[i];
        float x0 = a.x + b.x + s3 * c.x, x1 = a.y + b.y + s3 * c.y;
        float x2v = a.z + b.z + s3 * c.z, x3 = a.w + b.w + s3 * c.w;
        v[4 * i] = x0; v[4 * i + 1] = x1; v[4 * i + 2] = x2v; v[4 * i + 3] = x3;
        s += x0 + x1 + x2v + x3;
        sq += x0 * x0 + x1 * x1 + x2v * x2v + x3 * x3;
      }
      s += __shfl_xor(s, 1); s += __shfl_xor(s, 2);
      sq += __shfl_xor(sq, 1); sq += __shfl_xor(sq, 2);
      float mean = s * (1.f / 256.f);
      float var = sq * (1.f / 256.f) - mean * mean;
      float rsd = rsqrtf(var + 1e-5f);
      const float* g = ga1 + sub * 64; const float* be = bt1 + sub * 64;
      #pragma unroll
      for (int j8 = 0; j8 < 8; ++j8) {
        short8 pk;
        #pragma unroll
        for (int e = 0; e < 8; ++e) {
          int j = j8 * 8 + e;
          pk[e] = (short)f2b((v[j] - mean) * rsd * g[j] + be[j]);
        }
        int c = (sub * 8 + j8) ^ (row & 31);
        *(short8*)(As + row * 256 + c * 8) = pk;
      }
    }
    __syncthreads();

    // ---- A fragments into registers
    short8 a[16];
    #pragma unroll
    for (int kk = 0; kk < 16; ++kk)
      a[kk] = *(const short8*)(As + arow * 256 + ((kk * 2 + hl) ^ lm) * 8);
    __syncthreads();   // a-loads done; As region reusable for stages

  #define STAGE_B1(c_) { const char* s_ = (const char*)W1sel + (size_t)(c_) * 32768; \
    _Pragma("unroll") for (int j_ = 0; j_ < 4; ++j_) { int p_ = j_ * 8192 + t * 16; \
      gld_lds16(s_ + p_, ldsc + p_); } }
  #define STAGE_B2H(c_, h_) { const char* s_ = (const char*)W2sel + (size_t)(c_) * 32768 + (h_) * 16384; \
    _Pragma("unroll") for (int j_ = 0; j_ < 2; ++j_) { int p_ = j_ * 8192 + t * 16; \
      gld_lds16(s_ + p_, ldsc + 32768 + p_); } }

    f32x16 acc2[4];
    #pragma unroll
    for (int i = 0; i < 4; ++i)
      #pragma unroll
      for (int r = 0; r < 16; ++r) acc2[i][r] = 0.f;

    STAGE_B1(0);
    STAGE_B2H(0, 0);

    for (int nc = 0; nc < 16; ++nc) {
      // B1(nc) + B2 half0(nc) visible after drain
      asm volatile("s_waitcnt vmcnt(0)" ::: "memory");
      __builtin_amdgcn_sched_barrier(0);
      __builtin_amdgcn_s_barrier();
      float bias = bi1[nc * 64 + bl];
      // ---- GEMM1(nc)
      f32x16 acc1;
      #pragma unroll
      for (int r = 0; r < 16; ++r) acc1[r] = 0.f;
      #pragma unroll
      for (int kk = 0; kk < 16; ++kk) {
        short8 bf = *(const short8*)(B1s + bl * 256 + ((kk * 2 + hl) ^ lm) * 8);
        acc1 = __builtin_amdgcn_mfma_f32_32x32x16_bf16(a[kk], bf, acc1, 0, 0, 0);
      }
      asm volatile("s_waitcnt lgkmcnt(0)" ::: "memory");
      __builtin_amdgcn_sched_barrier(0);
      __builtin_amdgcn_s_barrier();          // B1s reads done on all waves
      if (nc < 15) STAGE_B1(nc + 1);         // async into B1s, drained next chunk
      // ---- Fwrite(nc)
      #pragma unroll
      for (int r = 0; r < 16; ++r) {
        int row = wm * 32 + (r & 3) + 8 * (r >> 2) + 4 * hl;
        Ff[row * 68 + bl] = f2b(fmaxf(acc1[r] + bias, 0.f));
      }
      asm volatile("s_waitcnt lgkmcnt(0)" ::: "memory");
      __builtin_amdgcn_sched_barrier(0);
      __builtin_amdgcn_s_barrier();          // F visible
      // ---- GEMM2 half 0 (k 0..31 of chunk)
      {
        short8 af[2];
        #pragma unroll
        for (int ksl = 0; ksl < 2; ++ksl)
          af[ksl] = *(const short8*)(Ff + frow * 68 + (ksl * 2 + hl) * 8);
        #pragma unroll
        for (int nt = 0; nt < 4; ++nt) {
          int n = wn * 128 + nt * 32 + lm;
          int pr2 = n >> 1;
          #pragma unroll
          for (int ksl = 0; ksl < 2; ++ksl) {
            int ci = (((n & 1) << 2) + ksl * 2 + hl) ^ (pr2 & 7);
            short8 bf = *(const short8*)(B2h + pr2 * 64 + ci * 8);
            acc2[nt] = __builtin_amdgcn_mfma_f32_32x32x16_bf16(af[ksl], bf, acc2[nt], 0, 0, 0);
          }
        }
      }
      asm volatile("s_waitcnt lgkmcnt(0)" ::: "memory");
      __builtin_amdgcn_sched_barrier(0);
      __builtin_amdgcn_s_barrier();          // B2h0 reads done
      STAGE_B2H(nc, 1);
      asm volatile("s_waitcnt vmcnt(0)" ::: "memory");
      __builtin_amdgcn_sched_barrier(0);
      __builtin_amdgcn_s_barrier();          // B2h1 (+B1(nc+1)) visible
      // ---- GEMM2 half 1 (k 32..63)
      {
        short8 af[2];
        #pragma unroll
        for (int ksl = 0; ksl < 2; ++ksl)
          af[ksl] = *(const short8*)(Ff + frow * 68 + (4 + ksl * 2 + hl) * 8);
        #pragma unroll
        for (int nt = 0; nt < 4; ++nt) {
          int n = wn * 128 + nt * 32 + lm;
          int pr2 = n >> 1;
          #pragma unroll
          for (int ksl = 0; ksl < 2; ++ksl) {
            int ci = (((n & 1) << 2) + ksl * 2 + hl) ^ (pr2 & 7);
            short8 bf = *(const short8*)(B2h + pr2 * 64 + ci * 8);
            acc2[nt] = __builtin_amdgcn_mfma_f32_32x32x16_bf16(af[ksl], bf, acc2[nt], 0, 0, 0);
          }
        }
      }
      asm volatile("s_waitcnt lgkmcnt(0)" ::: "memory");
      __builtin_amdgcn_sched_barrier(0);
      __builtin_amdgcn_s_barrier();          // B2h1 + Ff reads done
      if (nc < 15) STAGE_B2H(nc + 1, 0);     // drained at next chunk head
    }
    __syncthreads();

    // ---- Epilogue: restore normed residual into As, residual + LN
    if (wn == 0) {
      #pragma unroll
      for (int kk = 0; kk < 16; ++kk)
        *(short8*)(As + arow * 256 + ((kk * 2 + hl) ^ lm) * 8) = a[kk];
    }
    __syncthreads();

    float gv[4], bev[4], bf2v[4];
    #pragma unroll
    for (int nt = 0; nt < 4; ++nt) {
      int col = wn * 128 + nt * 32 + lm;
      gv[nt] = ga2[col]; bev[nt] = bt2[col]; bf2v[nt] = bi2[col];
    }
    #pragma unroll
    for (int nt = 0; nt < 4; ++nt) {
      int col = wn * 128 + nt * 32 + lm;
      #pragma unroll
      for (int r = 0; r < 16; ++r) {
        int row = wm * 32 + (r & 3) + 8 * (r >> 2) + 4 * hl;
        float res = b2f(As[row * 256 + ((col >> 3) ^ (row & 31)) * 8 + (col & 7)]);
        acc2[nt][r] += bf2v[nt] + res;
      }
    }
    __syncthreads();   // As reads done before LDS reuse below

    float* red_s = (float*)Ff;          // [2][128]
    float* red_q = red_s + 256;
    float* mrs   = red_q + 256;
    #pragma unroll
    for (int r = 0; r < 16; ++r) {
      int row = wm * 32 + (r & 3) + 8 * (r >> 2) + 4 * hl;
      float s = acc2[0][r] + acc2[1][r] + acc2[2][r] + acc2[3][r];
      float q = acc2[0][r] * acc2[0][r] + acc2[1][r] * acc2[1][r]
              + acc2[2][r] * acc2[2][r] + acc2[3][r] * acc2[3][r];
      #pragma unroll
      for (int m = 1; m < 32; m <<= 1) { s += __shfl_xor(s, m, 32); q += __shfl_xor(q, m, 32); }
      if (lm == 0) { red_s[wn * 128 + row] = s; red_q[wn * 128 + row] = q; }
    }
    __syncthreads();
    if (t < 128) {
      float s = red_s[t] + red_s[128 + t];
      float q = red_q[t] + red_q[128 + t];
      float mean = s * (1.f / 256.f);
      float var = q * (1.f / 256.f) - mean * mean;
      mrs[2 * t] = mean; mrs[2 * t + 1] = rsqrtf(var + 1e-5f);
    }
    __syncthreads();
    #pragma unroll
    for (int nt = 0; nt < 4; ++nt) {
      int col = wn * 128 + nt * 32 + lm;
      #pragma unroll
      for (int r = 0; r < 16; ++r) {
        int row = wm * 32 + (r & 3) + 8 * (r >> 2) + 4 * hl;
        float mean = mrs[2 * row], rstd = mrs[2 * row + 1];
        outp[(r0 + row) * 256 + col] = (acc2[nt][r] - mean) * rstd * gv[nt] + bev[nt];
      }
    }
    __syncthreads();   // tile boundary
  }
  #undef STAGE_B1
  #undef STAGE_B2H
}

// ---------------- host ----------------
extern "C" void kernel_launch(void* const* d_in, const int* in_sizes, int n_in,
                              void* d_out, int out_size, void* d_ws, size_t ws_size,
                              hipStream_t stream) {
  const float* x      = (const float*)d_in[0];
  const float* bg     = (const float*)d_in[1];
  const float* Wq     = (const float*)d_in[3];  const float* bq     = (const float*)d_in[4];
  const float* Wk     = (const float*)d_in[5];  const float* bk     = (const float*)d_in[6];
  const float* Wv     = (const float*)d_in[7];  const float* bv     = (const float*)d_in[8];
  const float* Wo     = (const float*)d_in[9];  const float* bo     = (const float*)d_in[10];
  const float* Wleft  = (const float*)d_in[11]; const float* bleft  = (const float*)d_in[12];
  const float* Wright = (const float*)d_in[13]; const float* bright = (const float*)d_in[14];
  const float* Wrk    = (const float*)d_in[15]; const float* brk    = (const float*)d_in[16];
  const float* Wrv    = (const float*)d_in[17]; const float* brv    = (const float*)d_in[18];
  const float* W1     = (const float*)d_in[19]; const float* b1     = (const float*)d_in[20];
  const float* W2     = (const float*)d_in[21]; const float* b2     = (const float*)d_in[22];
  const float* Wgf1   = (const float*)d_in[23]; const float* bgf1   = (const float*)d_in[24];
  const float* Wgf2   = (const float*)d_in[25]; const float* bgf2   = (const float*)d_in[26];
  const float* g1     = (const float*)d_in[27]; const float* g2     = (const float*)d_in[28];
  const float* gg1    = (const float*)d_in[29]; const float* gg2    = (const float*)d_in[30];
  const float* beta1  = (const float*)d_in[31]; const float* beta2  = (const float*)d_in[32];
  const float* betag1 = (const float*)d_in[33]; const float* betag2 = (const float*)d_in[34];

  float* ws   = (float*)d_ws;
  float* q    = ws;
  float* k    = ws + 131072;
  float* v    = ws + 262144;
  float* attn = ws + 393216;
  float* x2   = ws + 524288;
  float* aL   = ws + 655360;
  float* aR   = ws + 786432;
  u16* W1t  = (u16*)(ws + 917504);
  u16* W2H  = W1t + 262144;
  u16* W1tn = W2H + 262144;
  u16* W2Hn = W1tn + 262144;

  float* outx  = (float*)d_out;
  float* outbg = outx + 131072;

  hipFuncSetAttribute((const void*)k2_attn, hipFuncAttributeMaxDynamicSharedMemorySize, 79904);
  hipFuncSetAttribute((const void*)k4_kern, hipFuncAttributeMaxDynamicSharedMemorySize, 66560);

  k0_conv <<<2048, 256, 0, stream>>>(Wgf1, Wgf2, W1, W2, W1t, W2H, W1tn, W2Hn);
  k_proj3 <<<512, 256, 0, stream>>>(x, Wq, bq, Wk, bk, Wv, bv, q, k, v);
  k2_attn <<<512, 256, 79904, stream>>>(bg, q, k, v, Wrk, brk, Wrv, brv, attn);
  k_proj3 <<<512, 256, 0, stream>>>(attn, Wo, bo, Wleft, bleft, Wright, bright, x2, aL, aR);
  k4_kern <<<512, 512, 66560, stream>>>(bg, aL, aR, W1t, bgf1, W2H, bgf2,
                                        gg1, betag1, gg2, betag2, outbg,
                                        x, x2, W1tn, b1, W2Hn, b2,
                                        g1, beta1, g2, beta2, outx);
}

// Round 12
// 380.580 us; speedup vs baseline: 1.8358x; 1.0854x over previous
//
#include <hip/hip_runtime.h>

typedef unsigned short u16;
typedef unsigned int u32;
typedef __attribute__((ext_vector_type(8))) short short8;
typedef __attribute__((ext_vector_type(16))) float f32x16;

#define BB 4
#define NN 128
#define DD 256
#define DFF 1024

__device__ __forceinline__ u16 f2b(float f) {
  union { float f; u32 u; } c; c.f = f;
  u32 x = c.u;
  return (u16)((x + 0x7FFFu + ((x >> 16) & 1u)) >> 16);
}
__device__ __forceinline__ float b2f(u16 u) {
  union { u32 u; float f; } c; c.u = ((u32)u) << 16;
  return c.f;
}

__device__ __forceinline__ void gld_lds16(const void* g, void* l) {
  __builtin_amdgcn_global_load_lds(
      (const __attribute__((address_space(1))) unsigned int*)g,
      (__attribute__((address_space(3))) unsigned int*)l, 16, 0, 0);
}

// ---------------- K0: transpose+convert FFN weights (graph AND node) to bf16 ----
// W1t/W1tn: [n][256] pre-swizzled: k-chunk c=(k>>3)^(n&31) at c*8+(k&7).
// W2c/W2cn: chunk-major [nc][n][64] pre-swizzled: c=(kc>>3)^(n&7) at c*8+(kc&7).
__global__ void k0_conv(const float* __restrict__ Wgf1, const float* __restrict__ Wgf2,
                        const float* __restrict__ W1n, const float* __restrict__ W2n,
                        u16* __restrict__ W1t, u16* __restrict__ W2c,
                        u16* __restrict__ W1tn, u16* __restrict__ W2cn) {
  int gi = blockIdx.x * 256 + threadIdx.x;   // 0..524287
  const int i = gi & 262143;
  const bool second = gi >= 262144;
  const float* S1 = second ? W1n : Wgf1;
  const float* S2 = second ? W2n : Wgf2;
  u16* D1 = second ? W1tn : W1t;
  u16* D2 = second ? W2cn : W2c;
  int n1 = i & 1023, k1 = i >> 10;
  int c1 = ((k1 >> 3) ^ (n1 & 31)) & 31;
  D1[n1 * 256 + c1 * 8 + (k1 & 7)] = f2b(S1[k1 * DFF + n1]);
  int n2 = i & 255, k2 = i >> 8;
  int nc = k2 >> 6, kc = k2 & 63;
  int c2 = ((kc >> 3) ^ (n2 & 7)) & 7;
  D2[nc * 16384 + n2 * 64 + c2 * 8 + (kc & 7)] = f2b(S2[k2 * DD + n2]);
}

// ---------------- K1/K3a: three fused 256x256 projections ----------------
__global__ __launch_bounds__(256) void k_proj3(
    const float* __restrict__ in,
    const float* __restrict__ W0, const float* __restrict__ c0,
    const float* __restrict__ W1, const float* __restrict__ c1,
    const float* __restrict__ W2, const float* __restrict__ c2,
    float* __restrict__ o0, float* __restrict__ o1, float* __restrict__ o2) {
  __shared__ float row[DD];
  const int t = threadIdx.x; const int r = blockIdx.x;
  row[t] = in[r * DD + t];
  __syncthreads();
  float a0 = c0[t], a1 = c1[t], a2 = c2[t];
  for (int c = 0; c < DD; ++c) {
    float xv = row[c];
    a0 += xv * W0[c * DD + t];
    a1 += xv * W1[c * DD + t];
    a2 += xv * W2[c * DD + t];
  }
  o0[r * DD + t] = a0; o1[r * DD + t] = a1; o2[r * DD + t] = a2;
}

// ---------------- K2: fused relation attention (unchanged) ----------------
__global__ __launch_bounds__(256) void k2_attn(
    const float* __restrict__ bg, const float* __restrict__ qg,
    const float* __restrict__ kg, const float* __restrict__ vg,
    const float* __restrict__ Wrk, const float* __restrict__ brk,
    const float* __restrict__ Wrv, const float* __restrict__ brv,
    float* __restrict__ attn) {
  extern __shared__ char smem[];
  u16* bgt = (u16*)smem;                     // [128][260]
  float* qs = (float*)(smem + 66560);
  float* U  = (float*)(smem + 67584);
  float* sc = (float*)(smem + 75776);
  float* cb = (float*)(smem + 79872);
  const int t = threadIdx.x;
  const int blk = blockIdx.x;
  const int b = blk >> 7;
  const float* bgbase = bg + (long)blk * (NN * DD);

  qs[t] = qg[blk * DD + t];
  if (t < 8) {
    float s = 0.f;
    #pragma unroll
    for (int d = 0; d < 32; ++d) s += brk[t * 32 + d] * qg[blk * DD + t * 32 + d];
    cb[t] = s;
  }
  for (int i = 0; i < 32; ++i) {
    int e4 = i * 256 + t;
    float4 vv = *(const float4*)(bgbase + (long)e4 * 4);
    int e = e4 * 4; int row = e >> 8, col = e & 255;
    u32 p0 = (u32)f2b(vv.x) | ((u32)f2b(vv.y) << 16);
    u32 p1 = (u32)f2b(vv.z) | ((u32)f2b(vv.w) << 16);
    *(u32*)(bgt + row * 260 + col) = p0;
    *(u32*)(bgt + row * 260 + col + 2) = p1;
  }
  __syncthreads();
  {
    const float* wr = Wrk + t * DD;
    #pragma unroll
    for (int h = 0; h < 8; ++h) {
      float s = 0.f;
      #pragma unroll
      for (int d = 0; d < 32; ++d) s += wr[h * 32 + d] * qs[h * 32 + d];
      U[t * 8 + h] = s;
    }
  }
  __syncthreads();
  {
    const int h = t & 7, y0 = t >> 3;
    #pragma unroll
    for (int yy = 0; yy < 4; ++yy) {
      int y = y0 + yy * 32;
      float s = cb[h];
      const float* kr = kg + (long)(b * NN + y) * DD + h * 32;
      const float* qh = qs + h * 32;
      #pragma unroll
      for (int d = 0; d < 32; ++d) s += qh[d] * kr[d];
      const u16* br = bgt + y * 260;
      for (int c = 0; c < 256; c += 2) {
        u32 pk = *(const u32*)(br + c);
        s += b2f((u16)pk) * U[c * 8 + h] + b2f((u16)(pk >> 16)) * U[(c + 1) * 8 + h];
      }
      sc[y * 8 + h] = s * 0.1767766952966369f;
    }
  }
  __syncthreads();
  {
    const int h = t >> 5, ln = t & 31;
    float v0 = sc[ln * 8 + h], v1 = sc[(ln + 32) * 8 + h];
    float v2 = sc[(ln + 64) * 8 + h], v3 = sc[(ln + 96) * 8 + h];
    float mx = fmaxf(fmaxf(v0, v1), fmaxf(v2, v3));
    #pragma unroll
    for (int m = 1; m < 32; m <<= 1) mx = fmaxf(mx, __shfl_xor(mx, m, 32));
    float e0 = __expf(v0 - mx), e1 = __expf(v1 - mx);
    float e2 = __expf(v2 - mx), e3 = __expf(v3 - mx);
    float sm = e0 + e1 + e2 + e3;
    #pragma unroll
    for (int m = 1; m < 32; m <<= 1) sm += __shfl_xor(sm, m, 32);
    float inv = 1.f / sm;
    sc[ln * 8 + h] = e0 * inv; sc[(ln + 32) * 8 + h] = e1 * inv;
    sc[(ln + 64) * 8 + h] = e2 * inv; sc[(ln + 96) * 8 + h] = e3 * inv;
  }
  __syncthreads();
  {
    float acc[8];
    #pragma unroll
    for (int h = 0; h < 8; ++h) acc[h] = 0.f;
    for (int y = 0; y < 128; ++y) {
      float bv = b2f(bgt[y * 260 + t]);
      const float* pr = sc + y * 8;
      #pragma unroll
      for (int h = 0; h < 8; ++h) acc[h] += pr[h] * bv;
    }
    #pragma unroll
    for (int h = 0; h < 8; ++h) U[t * 8 + h] = acc[h];
  }
  __syncthreads();
  {
    const int h = t >> 5;
    float av = 0.f;
    for (int y = 0; y < 128; ++y) av += sc[y * 8 + h] * vg[(long)(b * NN + y) * DD + t];
    float ag = 0.f;
    for (int c = 0; c < 256; ++c) ag += U[c * 8 + h] * Wrv[c * DD + t];
    attn[blk * DD + t] = av + ag + brv[t];
  }
}

// ---------------- K4 v11 (= R7 pipeline + R9 merge, single kernel) ----------------
// 512 blocks x 512 thr (4M x 2N waves); blocks 0..3 run a second (node) tile.
// LDS 144KB: B1s[2] @0/@32K, B2s[2] @64K/@96K, Ff[128][64] @128K.
// As[128][256] (phase0/epilogue only) overlays bytes 0..64K.
// Per iter: syncthreads (drain prev stages + F writes) ; STAGE B1(nc+1),B2(nc) ;
//   GEMM1(nc) + GEMM2(nc-1) ; lgkm(0)+s_barrier ; Fwrite(nc).
__global__ __launch_bounds__(512, 2) void k4_kern(
    const float* __restrict__ bg, const float* __restrict__ aL, const float* __restrict__ aR,
    const u16* __restrict__ W1t, const float* __restrict__ bgf1,
    const u16* __restrict__ W2c, const float* __restrict__ bgf2,
    const float* __restrict__ gg1, const float* __restrict__ betag1,
    const float* __restrict__ gg2, const float* __restrict__ betag2,
    float* __restrict__ outbg,
    const float* __restrict__ x, const float* __restrict__ x2,
    const u16* __restrict__ W1tn, const float* __restrict__ b1n,
    const u16* __restrict__ W2cn, const float* __restrict__ b2n,
    const float* __restrict__ g1n, const float* __restrict__ beta1n,
    const float* __restrict__ g2n, const float* __restrict__ beta2n,
    float* __restrict__ outx) {
  extern __shared__ char ldsc[];
  u16* As = (u16*)ldsc;              // [128][256] (phase0 + epilogue)
  u16* Ff = (u16*)(ldsc + 131072);   // [128][64]  swizzled (c>>3)^(row&7)
  const int t = threadIdx.x;
  const int bid = blockIdx.x;
  const int l = t & 63, w = t >> 6, lm = l & 31, hl = l >> 5;
  const int wm = w & 3, wn = w >> 2;
  const int bl = wn * 32 + lm;
  const int frow = wm * 32 + lm;
  const int arow = wm * 32 + lm;

  const int ntile = (bid < 4) ? 2 : 1;
  for (int ti = 0; ti < ntile; ++ti) {
    const bool node = (ti == 1);
    const int blk = node ? bid : (((bid & 7) << 6) | (bid >> 3));  // XCD-chunked
    const long r0 = (long)blk * 128;

    const u16* W1sel = node ? W1tn : W1t;
    const u16* W2sel = node ? W2cn : W2c;
    const float* bi1 = node ? b1n : bgf1;
    const float* bi2 = node ? b2n : bgf2;
    const float* ga1 = node ? g1n : gg1;
    const float* bt1 = node ? beta1n : betag1;
    const float* ga2 = node ? g2n : gg2;
    const float* bt2 = node ? beta2n : betag2;
    float* outp = node ? outx : outbg;

    // ---- Phase 0: As = bf16(LN(residual sum)); 4 lanes/row, 128 rows
    {
      const int row = t >> 2, sub = t & 3;
      const long r = r0 + row;
      const int bx = (int)(r >> 7);
      const int by = (int)(((r >> 14) << 7) | (r & 127));
      const float4* pb = (const float4*)((node ? x : bg) + r * 256 + sub * 64);
      const float4* pl = node ? (const float4*)(x2 + r * 256 + sub * 64)
                              : (const float4*)(aL + (long)bx * 256 + sub * 64);
      const float4* pr = (const float4*)(aR + (long)(node ? 0 : by) * 256 + sub * 64);
      const float s3 = node ? 0.f : 1.f;
      float v[64];
      float s = 0.f, sq = 0.f;
      #pragma unroll
      for (int i = 0; i < 16; ++i) {
        float4 a = pb[i], b = pl[i], c = pr[i];
        float x0 = a.x + b.x + s3 * c.x, x1 = a.y + b.y + s3 * c.y;
        float x2v = a.z + b.z + s3 * c.z, x3 = a.w + b.w + s3 * c.w;
        v[4 * i] = x0; v[4 * i + 1] = x1; v[4 * i + 2] = x2v; v[4 * i + 3] = x3;
        s += x0 + x1 + x2v + x3;
        sq += x0 * x0 + x1 * x1 + x2v * x2v + x3 * x3;
      }
      s += __shfl_xor(s, 1); s += __shfl_xor(s, 2);
      sq += __shfl_xor(sq, 1); sq += __shfl_xor(sq, 2);
      float mean = s * (1.f / 256.f);
      float var = sq * (1.f / 256.f) - mean * mean;
      float rsd = rsqrtf(var + 1e-5f);
      const float* g = ga1 + sub * 64; const float* be = bt1 + sub * 64;
      #pragma unroll
      for (int j8 = 0; j8 < 8; ++j8) {
        short8 pk;
        #pragma unroll
        for (int e = 0; e < 8; ++e) {
          int j = j8 * 8 + e;
          pk[e] = (short)f2b((v[j] - mean) * rsd * g[j] + be[j]);
        }
        int c = (sub * 8 + j8) ^ (row & 31);
        *(short8*)(As + row * 256 + c * 8) = pk;
      }
    }
    __syncthreads();

    // ---- A fragments into registers (rows wm*32+lm; duplicated across wn)
    short8 a[16];
    #pragma unroll
    for (int kk = 0; kk < 16; ++kk)
      a[kk] = *(const short8*)(As + arow * 256 + ((kk * 2 + hl) ^ lm) * 8);
    __syncthreads();  // a-loads done on all waves; As region now reusable for stages

  #define STAGE_B1(c_) { const char* s_ = (const char*)W1sel + (size_t)(c_) * 32768; \
    char* d_ = ldsc + ((c_) & 1) * 32768; \
    _Pragma("unroll") for (int j_ = 0; j_ < 4; ++j_) { int p_ = j_ * 8192 + t * 16; \
      gld_lds16(s_ + p_, d_ + p_); } }
  #define STAGE_B2(c_) { const char* s_ = (const char*)W2sel + (size_t)(c_) * 32768; \
    char* d_ = ldsc + 65536 + ((c_) & 1) * 32768; \
    _Pragma("unroll") for (int j_ = 0; j_ < 4; ++j_) { int p_ = j_ * 8192 + t * 16; \
      gld_lds16(s_ + p_, d_ + p_); } }

    f32x16 acc2[4];
    #pragma unroll
    for (int i = 0; i < 4; ++i)
      #pragma unroll
      for (int r = 0; r < 16; ++r) acc2[i][r] = 0.f;

    STAGE_B1(0);   // drained by first loop barrier

    for (int nc = 0; nc <= 16; ++nc) {
      // drains: stages issued last iter (B1(nc), B2(nc-1)) + F(nc-1) ds_writes
      __syncthreads();
      float bias = 0.f;
      if (nc < 16) bias = bi1[nc * 64 + bl];
      if (nc < 15) STAGE_B1(nc + 1);
      if (nc < 16) STAGE_B2(nc);
      f32x16 acc1;
      if (nc < 16) {
        // ---- GEMM1(nc): acc1 = a @ W1chunk
        const u16* B1cur = (const u16*)(ldsc + (nc & 1) * 32768);
        #pragma unroll
        for (int r = 0; r < 16; ++r) acc1[r] = 0.f;
        #pragma unroll
        for (int kk = 0; kk < 16; ++kk) {
          short8 bf = *(const short8*)(B1cur + bl * 256 + ((kk * 2 + hl) ^ lm) * 8);
          acc1 = __builtin_amdgcn_mfma_f32_32x32x16_bf16(a[kk], bf, acc1, 0, 0, 0);
        }
      }
      if (nc > 0) {
        // ---- GEMM2(nc-1): acc2 += F(nc-1) @ W2chunk(nc-1)
        const u16* B2cur = (const u16*)(ldsc + 65536 + ((nc - 1) & 1) * 32768);
        short8 af[4];
        #pragma unroll
        for (int ks = 0; ks < 4; ++ks)
          af[ks] = *(const short8*)(Ff + frow * 64 + (((ks * 2 + hl) ^ (lm & 7)) * 8));
        #pragma unroll
        for (int nt = 0; nt < 4; ++nt) {
          int n = wn * 128 + nt * 32 + lm;
          #pragma unroll
          for (int ks = 0; ks < 4; ++ks) {
            short8 bf = *(const short8*)(B2cur + n * 64 + (((ks * 2 + hl) ^ (lm & 7)) * 8));
            acc2[nt] = __builtin_amdgcn_mfma_f32_32x32x16_bf16(af[ks], bf, acc2[nt], 0, 0, 0);
          }
        }
      }
      if (nc < 16) {
        // F reads of GEMM2(nc-1) must finish before Fwrite(nc); LDS-only barrier
        asm volatile("s_waitcnt lgkmcnt(0)" ::: "memory");
        __builtin_amdgcn_sched_barrier(0);
        __builtin_amdgcn_s_barrier();
        #pragma unroll
        for (int r = 0; r < 16; ++r) {
          int row = wm * 32 + (r & 3) + 8 * (r >> 2) + 4 * hl;
          Ff[row * 64 + ((bl >> 3) ^ (row & 7)) * 8 + (bl & 7)] = f2b(fmaxf(acc1[r] + bias, 0.f));
        }
      }
    }
    __syncthreads();

    // ---- Epilogue: restore normed residual into As (stage bufs dead), + LN
    if (wn == 0) {
      #pragma unroll
      for (int kk = 0; kk < 16; ++kk)
        *(short8*)(As + arow * 256 + ((kk * 2 + hl) ^ lm) * 8) = a[kk];
    }
    __syncthreads();

    float gv[4], bev[4], bf2v[4];
    #pragma unroll
    for (int nt = 0; nt < 4; ++nt) {
      int col = wn * 128 + nt * 32 + lm;
      gv[nt] = ga2[col]; bev[nt] = bt2[col]; bf2v[nt] = bi2[col];
    }
    #pragma unroll
    for (int nt = 0; nt < 4; ++nt) {
      int col = wn * 128 + nt * 32 + lm;
      #pragma unroll
      for (int r = 0; r < 16; ++r) {
        int row = wm * 32 + (r & 3) + 8 * (r >> 2) + 4 * hl;
        float res = b2f(As[row * 256 + ((col >> 3) ^ (row & 31)) * 8 + (col & 7)]);
        acc2[nt][r] += bf2v[nt] + res;
      }
    }
    __syncthreads();   // As reads done before LDS reuse below

    float* red_s = (float*)Ff;
    float* red_q = red_s + 256;
    float* mrs   = red_q + 256;
    #pragma unroll
    for (int r = 0; r < 16; ++r) {
      int row = wm * 32 + (r & 3) + 8 * (r >> 2) + 4 * hl;
      float s = acc2[0][r] + acc2[1][r] + acc2[2][r] + acc2[3][r];
      float q = acc2[0][r] * acc2[0][r] + acc2[1][r] * acc2[1][r]
              + acc2[2][r] * acc2[2][r] + acc2[3][r] * acc2[3][r];
      #pragma unroll
      for (int m = 1; m < 32; m <<= 1) { s += __shfl_xor(s, m, 32); q += __shfl_xor(q, m, 32); }
      if (lm == 0) { red_s[wn * 128 + row] = s; red_q[wn * 128 + row] = q; }
    }
    __syncthreads();
    if (t < 128) {
      float s = red_s[t] + red_s[128 + t];
      float q = red_q[t] + red_q[128 + t];
      float mean = s * (1.f / 256.f);
      float var = q * (1.f / 256.f) - mean * mean;
      mrs[2 * t] = mean; mrs[2 * t + 1] = rsqrtf(var + 1e-5f);
    }
    __syncthreads();
    #pragma unroll
    for (int nt = 0; nt < 4; ++nt) {
      int col = wn * 128 + nt * 32 + lm;
      #pragma unroll
      for (int r = 0; r < 16; ++r) {
        int row = wm * 32 + (r & 3) + 8 * (r >> 2) + 4 * hl;
        float mean = mrs[2 * row], rstd = mrs[2 * row + 1];
        outp[(r0 + row) * 256 + col] = (acc2[nt][r] - mean) * rstd * gv[nt] + bev[nt];
      }
    }
    __syncthreads();   // tile boundary: all LDS reads done before next phase0
  }
  #undef STAGE_B1
  #undef STAGE_B2
}

// ---------------- host ----------------
extern "C" void kernel_launch(void* const* d_in, const int* in_sizes, int n_in,
                              void* d_out, int out_size, void* d_ws, size_t ws_size,
                              hipStream_t stream) {
  const float* x      = (const float*)d_in[0];
  const float* bg     = (const float*)d_in[1];
  const float* Wq     = (const float*)d_in[3];  const float* bq     = (const float*)d_in[4];
  const float* Wk     = (const float*)d_in[5];  const float* bk     = (const float*)d_in[6];
  const float* Wv     = (const float*)d_in[7];  const float* bv     = (const float*)d_in[8];
  const float* Wo     = (const float*)d_in[9];  const float* bo     = (const float*)d_in[10];
  const float* Wleft  = (const float*)d_in[11]; const float* bleft  = (const float*)d_in[12];
  const float* Wright = (const float*)d_in[13]; const float* bright = (const float*)d_in[14];
  const float* Wrk    = (const float*)d_in[15]; const float* brk    = (const float*)d_in[16];
  const float* Wrv    = (const float*)d_in[17]; const float* brv    = (const float*)d_in[18];
  const float* W1     = (const float*)d_in[19]; const float* b1     = (const float*)d_in[20];
  const float* W2     = (const float*)d_in[21]; const float* b2     = (const float*)d_in[22];
  const float* Wgf1   = (const float*)d_in[23]; const float* bgf1   = (const float*)d_in[24];
  const float* Wgf2   = (const float*)d_in[25]; const float* bgf2   = (const float*)d_in[26];
  const float* g1     = (const float*)d_in[27]; const float* g2     = (const float*)d_in[28];
  const float* gg1    = (const float*)d_in[29]; const float* gg2    = (const float*)d_in[30];
  const float* beta1  = (const float*)d_in[31]; const float* beta2  = (const float*)d_in[32];
  const float* betag1 = (const float*)d_in[33]; const float* betag2 = (const float*)d_in[34];

  float* ws   = (float*)d_ws;
  float* q    = ws;
  float* k    = ws + 131072;
  float* v    = ws + 262144;
  float* attn = ws + 393216;
  float* x2   = ws + 524288;
  float* aL   = ws + 655360;
  float* aR   = ws + 786432;
  u16* W1t  = (u16*)(ws + 917504);
  u16* W2c  = W1t + 262144;
  u16* W1tn = W2c + 262144;
  u16* W2cn = W1tn + 262144;

  float* outx  = (float*)d_out;
  float* outbg = outx + 131072;

  hipFuncSetAttribute((const void*)k2_attn, hipFuncAttributeMaxDynamicSharedMemorySize, 79904);
  hipFuncSetAttribute((const void*)k4_kern, hipFuncAttributeMaxDynamicSharedMemorySize, 147456);

  k0_conv <<<2048, 256, 0, stream>>>(Wgf1, Wgf2, W1, W2, W1t, W2c, W1tn, W2cn);
  k_proj3 <<<512, 256, 0, stream>>>(x, Wq, bq, Wk, bk, Wv, bv, q, k, v);
  k2_attn <<<512, 256, 79904, stream>>>(bg, q, k, v, Wrk, brk, Wrv, brv, attn);
  k_proj3 <<<512, 256, 0, stream>>>(attn, Wo, bo, Wleft, bleft, Wright, bright, x2, aL, aR);
  k4_kern <<<512, 512, 147456, stream>>>(bg, aL, aR, W1t, bgf1, W2c, bgf2,
                                         gg1, betag1, gg2, betag2, outbg,
                                         x, x2, W1tn, b1, W2cn, b2,
                                         g1, beta1, g2, beta2, outx);
}

// Round 13
// 335.545 us; speedup vs baseline: 2.0822x; 1.1342x over previous
//
#include <hip/hip_runtime.h>

typedef unsigned short u16;
typedef unsigned int u32;
typedef __attribute__((ext_vector_type(8))) short short8;
typedef __attribute__((ext_vector_type(16))) float f32x16;

#define BB 4
#define NN 128
#define DD 256
#define DFF 1024

__device__ __forceinline__ u16 f2b(float f) {
  union { float f; u32 u; } c; c.f = f;
  u32 x = c.u;
  return (u16)((x + 0x7FFFu + ((x >> 16) & 1u)) >> 16);
}
__device__ __forceinline__ float b2f(u16 u) {
  union { u32 u; float f; } c; c.u = ((u32)u) << 16;
  return c.f;
}

__device__ __forceinline__ void gld_lds16(const void* g, void* l) {
  __builtin_amdgcn_global_load_lds(
      (const __attribute__((address_space(1))) unsigned int*)g,
      (__attribute__((address_space(3))) unsigned int*)l, 16, 0, 0);
}

// ---------------- K0: graph FFN weights -> pre-swizzled bf16 MFMA layouts ----------
// W1t: [n][256] pre-swizzled: k-chunk c=(k>>3)^(n&31) at c*8+(k&7).   (n<1024)
// W2c: chunk-major [nc][n][64] pre-swizzled: c=(kc>>3)^(n&7) at c*8+(kc&7).
__global__ void k0_conv(const float* __restrict__ Wgf1, const float* __restrict__ Wgf2,
                        u16* __restrict__ W1t, u16* __restrict__ W2c) {
  int i = blockIdx.x * 256 + threadIdx.x;  // 0..262143
  int n1 = i & 1023, k1 = i >> 10;         // coalesced read of Wgf1 row k1
  int c1 = ((k1 >> 3) ^ (n1 & 31)) & 31;
  W1t[n1 * 256 + c1 * 8 + (k1 & 7)] = f2b(Wgf1[k1 * DFF + n1]);
  int n2 = i & 255, k2 = i >> 8;           // coalesced read of Wgf2 row k2
  int nc = k2 >> 6, kc = k2 & 63;
  int c2 = ((kc >> 3) ^ (n2 & 7)) & 7;
  W2c[nc * 16384 + n2 * 64 + c2 * 8 + (kc & 7)] = f2b(Wgf2[k2 * DD + n2]);
}

// ---------------- K0b: plain bf16 copies of proj + node-FFN weights ----------------
// WB layout (u16 elements): Wq@0 Wk@65536 Wv@131072 Wo@196608 Wl@262144 Wr@327680
//                           W1@393216 (262144 el)  W2@655360 (262144 el)
__global__ void k0b_conv(const float* __restrict__ Wq, const float* __restrict__ Wk,
                         const float* __restrict__ Wv, const float* __restrict__ Wo,
                         const float* __restrict__ Wl, const float* __restrict__ Wr,
                         const float* __restrict__ W1, const float* __restrict__ W2,
                         u16* __restrict__ WB) {
  int gi = blockIdx.x * 256 + threadIdx.x;   // 0..917503
  const float* s; int off;
  if (gi < 393216) {
    int seg = gi >> 16; off = gi & 65535;
    s = seg == 0 ? Wq : seg == 1 ? Wk : seg == 2 ? Wv : seg == 3 ? Wo : seg == 4 ? Wl : Wr;
  } else if (gi < 655360) { s = W1; off = gi - 393216; }
  else { s = W2; off = gi - 655360; }
  WB[gi] = f2b(s[off]);
}

// ---------------- K1/K3a: three fused 256x256 projections (bf16 weights) ----------
__global__ __launch_bounds__(256) void k_proj3(
    const float* __restrict__ in,
    const u16* __restrict__ W0, const float* __restrict__ c0,
    const u16* __restrict__ W1, const float* __restrict__ c1,
    const u16* __restrict__ W2, const float* __restrict__ c2,
    float* __restrict__ o0, float* __restrict__ o1, float* __restrict__ o2) {
  __shared__ float row[DD];
  const int t = threadIdx.x; const int r = blockIdx.x;
  row[t] = in[r * DD + t];
  __syncthreads();
  float a0 = c0[t], a1 = c1[t], a2 = c2[t];
  for (int c = 0; c < DD; ++c) {
    float xv = row[c];
    a0 += xv * b2f(W0[c * DD + t]);
    a1 += xv * b2f(W1[c * DD + t]);
    a2 += xv * b2f(W2[c * DD + t]);
  }
  o0[r * DD + t] = a0; o1[r * DD + t] = a1; o2[r * DD + t] = a2;
}

// ---------------- K2: fused relation attention (unchanged, fp32 weights) ----------
__global__ __launch_bounds__(256) void k2_attn(
    const float* __restrict__ bg, const float* __restrict__ qg,
    const float* __restrict__ kg, const float* __restrict__ vg,
    const float* __restrict__ Wrk, const float* __restrict__ brk,
    const float* __restrict__ Wrv, const float* __restrict__ brv,
    float* __restrict__ attn) {
  extern __shared__ char smem[];
  u16* bgt = (u16*)smem;                     // [128][260]
  float* qs = (float*)(smem + 66560);
  float* U  = (float*)(smem + 67584);
  float* sc = (float*)(smem + 75776);
  float* cb = (float*)(smem + 79872);
  const int t = threadIdx.x;
  const int blk = blockIdx.x;
  const int b = blk >> 7;
  const float* bgbase = bg + (long)blk * (NN * DD);

  qs[t] = qg[blk * DD + t];
  if (t < 8) {
    float s = 0.f;
    #pragma unroll
    for (int d = 0; d < 32; ++d) s += brk[t * 32 + d] * qg[blk * DD + t * 32 + d];
    cb[t] = s;
  }
  for (int i = 0; i < 32; ++i) {
    int e4 = i * 256 + t;
    float4 vv = *(const float4*)(bgbase + (long)e4 * 4);
    int e = e4 * 4; int row = e >> 8, col = e & 255;
    u32 p0 = (u32)f2b(vv.x) | ((u32)f2b(vv.y) << 16);
    u32 p1 = (u32)f2b(vv.z) | ((u32)f2b(vv.w) << 16);
    *(u32*)(bgt + row * 260 + col) = p0;
    *(u32*)(bgt + row * 260 + col + 2) = p1;
  }
  __syncthreads();
  {
    const float* wr = Wrk + t * DD;
    #pragma unroll
    for (int h = 0; h < 8; ++h) {
      float s = 0.f;
      #pragma unroll
      for (int d = 0; d < 32; ++d) s += wr[h * 32 + d] * qs[h * 32 + d];
      U[t * 8 + h] = s;
    }
  }
  __syncthreads();
  {
    const int h = t & 7, y0 = t >> 3;
    #pragma unroll
    for (int yy = 0; yy < 4; ++yy) {
      int y = y0 + yy * 32;
      float s = cb[h];
      const float* kr = kg + (long)(b * NN + y) * DD + h * 32;
      const float* qh = qs + h * 32;
      #pragma unroll
      for (int d = 0; d < 32; ++d) s += qh[d] * kr[d];
      const u16* br = bgt + y * 260;
      for (int c = 0; c < 256; c += 2) {
        u32 pk = *(const u32*)(br + c);
        s += b2f((u16)pk) * U[c * 8 + h] + b2f((u16)(pk >> 16)) * U[(c + 1) * 8 + h];
      }
      sc[y * 8 + h] = s * 0.1767766952966369f;
    }
  }
  __syncthreads();
  {
    const int h = t >> 5, ln = t & 31;
    float v0 = sc[ln * 8 + h], v1 = sc[(ln + 32) * 8 + h];
    float v2 = sc[(ln + 64) * 8 + h], v3 = sc[(ln + 96) * 8 + h];
    float mx = fmaxf(fmaxf(v0, v1), fmaxf(v2, v3));
    #pragma unroll
    for (int m = 1; m < 32; m <<= 1) mx = fmaxf(mx, __shfl_xor(mx, m, 32));
    float e0 = __expf(v0 - mx), e1 = __expf(v1 - mx);
    float e2 = __expf(v2 - mx), e3 = __expf(v3 - mx);
    float sm = e0 + e1 + e2 + e3;
    #pragma unroll
    for (int m = 1; m < 32; m <<= 1) sm += __shfl_xor(sm, m, 32);
    float inv = 1.f / sm;
    sc[ln * 8 + h] = e0 * inv; sc[(ln + 32) * 8 + h] = e1 * inv;
    sc[(ln + 64) * 8 + h] = e2 * inv; sc[(ln + 96) * 8 + h] = e3 * inv;
  }
  __syncthreads();
  {
    float acc[8];
    #pragma unroll
    for (int h = 0; h < 8; ++h) acc[h] = 0.f;
    for (int y = 0; y < 128; ++y) {
      float bv = b2f(bgt[y * 260 + t]);
      const float* pr = sc + y * 8;
      #pragma unroll
      for (int h = 0; h < 8; ++h) acc[h] += pr[h] * bv;
    }
    #pragma unroll
    for (int h = 0; h < 8; ++h) U[t * 8 + h] = acc[h];
  }
  __syncthreads();
  {
    const int h = t >> 5;
    float av = 0.f;
    for (int y = 0; y < 128; ++y) av += sc[y * 8 + h] * vg[(long)(b * NN + y) * DD + t];
    float ag = 0.f;
    for (int c = 0; c < 256; ++c) ag += U[c * 8 + h] * Wrv[c * DD + t];
    attn[blk * DD + t] = av + ag + brv[t];
  }
}

// ---------------- K3b: node branch (bf16 weights) ----------------
__global__ __launch_bounds__(256) void k3_node(
    const float* __restrict__ x, const float* __restrict__ x2,
    const u16* __restrict__ W1, const float* __restrict__ b1,
    const u16* __restrict__ W2, const float* __restrict__ b2,
    const float* __restrict__ g1, const float* __restrict__ beta1,
    const float* __restrict__ g2, const float* __restrict__ beta2,
    float* __restrict__ outx) {
  __shared__ float xn1[DD];
  __shared__ float h1[DFF];
  __shared__ float red[8];
  const int t = threadIdx.x; const int r = blockIdx.x;
  float xv = x[r * DD + t] + x2[r * DD + t];
  float s = xv, sq = xv * xv;
  #pragma unroll
  for (int m = 1; m < 64; m <<= 1) { s += __shfl_xor(s, m); sq += __shfl_xor(sq, m); }
  if ((t & 63) == 0) { red[t >> 6] = s; red[4 + (t >> 6)] = sq; }
  __syncthreads();
  s = red[0] + red[1] + red[2] + red[3]; sq = red[4] + red[5] + red[6] + red[7];
  float mean = s * (1.f / 256.f), var = sq * (1.f / 256.f) - mean * mean;
  float rs = rsqrtf(var + 1e-5f);
  float xn = (xv - mean) * rs * g1[t] + beta1[t];
  xn1[t] = xn;
  __syncthreads();
  #pragma unroll
  for (int i = 0; i < 4; ++i) {
    int j = i * 256 + t;
    float hv = b1[j];
    for (int c = 0; c < DD; ++c) hv += xn1[c] * b2f(W1[c * DFF + j]);
    h1[j] = hv > 0.f ? hv : 0.f;
  }
  __syncthreads();
  float yv = b2[t];
  for (int c = 0; c < DFF; ++c) yv += h1[c] * b2f(W2[c * DD + t]);
  float t2 = xn + yv;
  s = t2; sq = t2 * t2;
  #pragma unroll
  for (int m = 1; m < 64; m <<= 1) { s += __shfl_xor(s, m); sq += __shfl_xor(sq, m); }
  if ((t & 63) == 0) { red[t >> 6] = s; red[4 + (t >> 6)] = sq; }
  __syncthreads();
  s = red[0] + red[1] + red[2] + red[3]; sq = red[4] + red[5] + red[6] + red[7];
  mean = s * (1.f / 256.f); var = sq * (1.f / 256.f) - mean * mean;
  rs = rsqrtf(var + 1e-5f);
  outx[r * DD + t] = (t2 - mean) * rs * g2[t] + beta2[t];
}

// ---------------- K4 (R7-exact): 1-barrier software pipeline GEMM1(nc) || GEMM2(nc-1)
// 512 blocks x 512 thr (4M x 2N waves).  LDS 144KB:
//   B1s[2] @0/@32K (dbuf), B2s[2] @64K/@96K (dbuf), Ff [128][64]u16 @128K (16KB).
//   As[128][256] (phase0/epilogue only) overlays bytes 0..64K.
__global__ __launch_bounds__(512, 2) void k4_graph(
    const float* __restrict__ bg, const float* __restrict__ aL, const float* __restrict__ aR,
    const u16* __restrict__ W1t, const float* __restrict__ bgf1,
    const u16* __restrict__ W2c, const float* __restrict__ bgf2,
    const float* __restrict__ gg1, const float* __restrict__ betag1,
    const float* __restrict__ gg2, const float* __restrict__ betag2,
    float* __restrict__ outbg) {
  extern __shared__ char ldsc[];
  u16* As = (u16*)ldsc;              // [128][256] (phase0 + epilogue)
  u16* Ff = (u16*)(ldsc + 131072);   // [128][64]  swizzled (c>>3)^(row&7)
  const int t = threadIdx.x;
  const int blk = ((blockIdx.x & 7) << 6) | (blockIdx.x >> 3);  // XCD-chunked
  const long r0 = (long)blk * 128;
  const int l = t & 63, w = t >> 6, lm = l & 31, hl = l >> 5;
  const int wm = w & 3, wn = w >> 2;

  // ---- Phase 0: As = bf16(LN(bg + aL + aR)); 4 lanes/row, 128 rows
  {
    const int row = t >> 2, sub = t & 3;
    const long r = r0 + row;
    const int bx = (int)(r >> 7);
    const int by = (int)(((r >> 14) << 7) | (r & 127));
    const float4* pb = (const float4*)(bg + r * 256 + sub * 64);
    const float4* pl = (const float4*)(aL + (long)bx * 256 + sub * 64);
    const float4* pr = (const float4*)(aR + (long)by * 256 + sub * 64);
    float v[64];
    float s = 0.f, sq = 0.f;
    #pragma unroll
    for (int i = 0; i < 16; ++i) {
      float4 a = pb[i], b = pl[i], c = pr[i];
      float x0 = a.x + b.x + c.x, x1 = a.y + b.y + c.y;
      float x2v = a.z + b.z + c.z, x3 = a.w + b.w + c.w;
      v[4 * i] = x0; v[4 * i + 1] = x1; v[4 * i + 2] = x2v; v[4 * i + 3] = x3;
      s += x0 + x1 + x2v + x3;
      sq += x0 * x0 + x1 * x1 + x2v * x2v + x3 * x3;
    }
    s += __shfl_xor(s, 1); s += __shfl_xor(s, 2);
    sq += __shfl_xor(sq, 1); sq += __shfl_xor(sq, 2);
    float mean = s * (1.f / 256.f);
    float var = sq * (1.f / 256.f) - mean * mean;
    float rsd = rsqrtf(var + 1e-5f);
    const float* g = gg1 + sub * 64; const float* be = betag1 + sub * 64;
    #pragma unroll
    for (int j8 = 0; j8 < 8; ++j8) {
      short8 pk;
      #pragma unroll
      for (int e = 0; e < 8; ++e) {
        int j = j8 * 8 + e;
        pk[e] = (short)f2b((v[j] - mean) * rsd * g[j] + be[j]);
      }
      int c = (sub * 8 + j8) ^ (row & 31);
      *(short8*)(As + row * 256 + c * 8) = pk;
    }
  }
  __syncthreads();

  // ---- A fragments into registers (rows wm*32+lm; duplicated across wn)
  short8 a[16];
  const int arow = wm * 32 + lm;
  #pragma unroll
  for (int kk = 0; kk < 16; ++kk)
    a[kk] = *(const short8*)(As + arow * 256 + ((kk * 2 + hl) ^ lm) * 8);
  __syncthreads();  // a-loads done on all waves; As region now reusable for stages

  #define STAGE_B1(c_) { const char* s_ = (const char*)W1t + (size_t)(c_) * 32768; \
    char* d_ = ldsc + ((c_) & 1) * 32768; \
    _Pragma("unroll") for (int j_ = 0; j_ < 4; ++j_) { int p_ = j_ * 8192 + t * 16; \
      gld_lds16(s_ + p_, d_ + p_); } }
  #define STAGE_B2(c_) { const char* s_ = (const char*)W2c + (size_t)(c_) * 32768; \
    char* d_ = ldsc + 65536 + ((c_) & 1) * 32768; \
    _Pragma("unroll") for (int j_ = 0; j_ < 4; ++j_) { int p_ = j_ * 8192 + t * 16; \
      gld_lds16(s_ + p_, d_ + p_); } }

  f32x16 acc2[4];
  #pragma unroll
  for (int i = 0; i < 4; ++i)
    #pragma unroll
    for (int r = 0; r < 16; ++r) acc2[i][r] = 0.f;

  const int bl = wn * 32 + lm;   // F-col within chunk (GEMM1)
  const int frow = wm * 32 + lm; // F row read by this lane (GEMM2)

  STAGE_B1(0);   // drained by first loop barrier

  for (int nc = 0; nc <= 16; ++nc) {
    // drains: stages issued last iter (B1(nc), B2(nc-1)) + F(nc-1) ds_writes
    __syncthreads();
    float bias = 0.f;
    if (nc < 16) bias = bgf1[nc * 64 + bl];     // oldest vmcnt entry
    if (nc < 15) STAGE_B1(nc + 1);
    if (nc < 16) STAGE_B2(nc);
    f32x16 acc1;
    if (nc < 16) {
      // ---- GEMM1(nc): acc1 = bg1 @ W1chunk
      const u16* B1cur = (const u16*)(ldsc + (nc & 1) * 32768);
      #pragma unroll
      for (int r = 0; r < 16; ++r) acc1[r] = 0.f;
      #pragma unroll
      for (int kk = 0; kk < 16; ++kk) {
        short8 bf = *(const short8*)(B1cur + bl * 256 + ((kk * 2 + hl) ^ lm) * 8);
        acc1 = __builtin_amdgcn_mfma_f32_32x32x16_bf16(a[kk], bf, acc1, 0, 0, 0);
      }
    }
    if (nc > 0) {
      // ---- GEMM2(nc-1): acc2 += F(nc-1) @ W2chunk(nc-1)
      const u16* B2cur = (const u16*)(ldsc + 65536 + ((nc - 1) & 1) * 32768);
      short8 af[4];
      #pragma unroll
      for (int ks = 0; ks < 4; ++ks)
        af[ks] = *(const short8*)(Ff + frow * 64 + (((ks * 2 + hl) ^ (lm & 7)) * 8));
      #pragma unroll
      for (int nt = 0; nt < 4; ++nt) {
        int n = wn * 128 + nt * 32 + lm;
        #pragma unroll
        for (int ks = 0; ks < 4; ++ks) {
          short8 bf = *(const short8*)(B2cur + n * 64 + (((ks * 2 + hl) ^ (lm & 7)) * 8));
          acc2[nt] = __builtin_amdgcn_mfma_f32_32x32x16_bf16(af[ks], bf, acc2[nt], 0, 0, 0);
        }
      }
    }
    if (nc < 16) {
      // F reads of GEMM2(nc-1) must finish before Fwrite(nc); LDS-only barrier
      asm volatile("s_waitcnt lgkmcnt(0)" ::: "memory");
      __builtin_amdgcn_sched_barrier(0);
      __builtin_amdgcn_s_barrier();
      #pragma unroll
      for (int r = 0; r < 16; ++r) {
        int row = wm * 32 + (r & 3) + 8 * (r >> 2) + 4 * hl;
        Ff[row * 64 + ((bl >> 3) ^ (row & 7)) * 8 + (bl & 7)] = f2b(fmaxf(acc1[r] + bias, 0.f));
      }
    }
  }
  __syncthreads();

  // ---- Epilogue: restore bg1 into As (stage bufs dead), residual + LN
  if (wn == 0) {
    #pragma unroll
    for (int kk = 0; kk < 16; ++kk)
      *(short8*)(As + arow * 256 + ((kk * 2 + hl) ^ lm) * 8) = a[kk];
  }
  __syncthreads();

  const int c0 = wn * 128;
  float gv[4], bev[4], bf2v[4];
  #pragma unroll
  for (int nt = 0; nt < 4; ++nt) {
    int col = c0 + nt * 32 + lm;
    gv[nt] = gg2[col]; bev[nt] = betag2[col]; bf2v[nt] = bgf2[col];
  }
  #pragma unroll
  for (int nt = 0; nt < 4; ++nt) {
    int col = c0 + nt * 32 + lm;
    #pragma unroll
    for (int r = 0; r < 16; ++r) {
      int row = wm * 32 + (r & 3) + 8 * (r >> 2) + 4 * hl;
      float res = b2f(As[row * 256 + ((col >> 3) ^ (row & 31)) * 8 + (col & 7)]);
      acc2[nt][r] += bf2v[nt] + res;
    }
  }
  __syncthreads();   // As reads done before LDS reuse below

  float* red_s = (float*)Ff;
  float* red_q = red_s + 256;
  float* mrs   = red_q + 256;
  #pragma unroll
  for (int r = 0; r < 16; ++r) {
    int row = wm * 32 + (r & 3) + 8 * (r >> 2) + 4 * hl;
    float s = acc2[0][r] + acc2[1][r] + acc2[2][r] + acc2[3][r];
    float q = acc2[0][r] * acc2[0][r] + acc2[1][r] * acc2[1][r]
            + acc2[2][r] * acc2[2][r] + acc2[3][r] * acc2[3][r];
    #pragma unroll
    for (int m = 1; m < 32; m <<= 1) { s += __shfl_xor(s, m, 32); q += __shfl_xor(q, m, 32); }
    if (lm == 0) { red_s[wn * 128 + row] = s; red_q[wn * 128 + row] = q; }
  }
  __syncthreads();
  if (t < 128) {
    float s = red_s[t] + red_s[128 + t];
    float q = red_q[t] + red_q[128 + t];
    float mean = s * (1.f / 256.f);
    float var = q * (1.f / 256.f) - mean * mean;
    mrs[2 * t] = mean; mrs[2 * t + 1] = rsqrtf(var + 1e-5f);
  }
  __syncthreads();
  #pragma unroll
  for (int nt = 0; nt < 4; ++nt) {
    int col = c0 + nt * 32 + lm;
    #pragma unroll
    for (int r = 0; r < 16; ++r) {
      int row = wm * 32 + (r & 3) + 8 * (r >> 2) + 4 * hl;
      float mean = mrs[2 * row], rstd = mrs[2 * row + 1];
      outbg[(r0 + row) * 256 + col] = (acc2[nt][r] - mean) * rstd * gv[nt] + bev[nt];
    }
  }
  #undef STAGE_B1
  #undef STAGE_B2
}

// ---------------- host ----------------
extern "C" void kernel_launch(void* const* d_in, const int* in_sizes, int n_in,
                              void* d_out, int out_size, void* d_ws, size_t ws_size,
                              hipStream_t stream) {
  const float* x      = (const float*)d_in[0];
  const float* bg     = (const float*)d_in[1];
  const float* Wq     = (const float*)d_in[3];  const float* bq     = (const float*)d_in[4];
  const float* Wk     = (const float*)d_in[5];  const float* bk     = (const float*)d_in[6];
  const float* Wv     = (const float*)d_in[7];  const float* bv     = (const float*)d_in[8];
  const float* Wo     = (const float*)d_in[9];  const float* bo     = (const float*)d_in[10];
  const float* Wleft  = (const float*)d_in[11]; const float* bleft  = (const float*)d_in[12];
  const float* Wright = (const float*)d_in[13]; const float* bright = (const float*)d_in[14];
  const float* Wrk    = (const float*)d_in[15]; const float* brk    = (const float*)d_in[16];
  const float* Wrv    = (const float*)d_in[17]; const float* brv    = (const float*)d_in[18];
  const float* W1     = (const float*)d_in[19]; const float* b1     = (const float*)d_in[20];
  const float* W2     = (const float*)d_in[21]; const float* b2     = (const float*)d_in[22];
  const float* Wgf1   = (const float*)d_in[23]; const float* bgf1   = (const float*)d_in[24];
  const float* Wgf2   = (const float*)d_in[25]; const float* bgf2   = (const float*)d_in[26];
  const float* g1     = (const float*)d_in[27]; const float* g2     = (const float*)d_in[28];
  const float* gg1    = (const float*)d_in[29]; const float* gg2    = (const float*)d_in[30];
  const float* beta1  = (const float*)d_in[31]; const float* beta2  = (const float*)d_in[32];
  const float* betag1 = (const float*)d_in[33]; const float* betag2 = (const float*)d_in[34];

  float* ws   = (float*)d_ws;
  float* q    = ws;
  float* k    = ws + 131072;
  float* v    = ws + 262144;
  float* attn = ws + 393216;
  float* x2   = ws + 524288;
  float* aL   = ws + 655360;
  float* aR   = ws + 786432;
  u16* W1t = (u16*)(ws + 917504);       // 262144 u16
  u16* W2c = W1t + 262144;              // 262144 u16  -> ends at float 1179648
  u16* WB  = (u16*)(ws + 1179648);      // 917504 u16  -> ends at float 1638400

  float* outx  = (float*)d_out;
  float* outbg = outx + 131072;

  hipFuncSetAttribute((const void*)k2_attn,  hipFuncAttributeMaxDynamicSharedMemorySize, 79904);
  hipFuncSetAttribute((const void*)k4_graph, hipFuncAttributeMaxDynamicSharedMemorySize, 147456);

  k0_conv <<<1024, 256, 0, stream>>>(Wgf1, Wgf2, W1t, W2c);
  k0b_conv<<<3584, 256, 0, stream>>>(Wq, Wk, Wv, Wo, Wleft, Wright, W1, W2, WB);
  k_proj3 <<<512, 256, 0, stream>>>(x, WB, bq, WB + 65536, bk, WB + 131072, bv, q, k, v);
  k2_attn <<<512, 256, 79904, stream>>>(bg, q, k, v, Wrk, brk, Wrv, brv, attn);
  k_proj3 <<<512, 256, 0, stream>>>(attn, WB + 196608, bo, WB + 262144, bleft,
                                    WB + 327680, bright, x2, aL, aR);
  k3_node <<<512, 256, 0, stream>>>(x, x2, WB + 393216, b1, WB + 655360, b2,
                                    g1, beta1, g2, beta2, outx);
  k4_graph<<<512, 512, 147456, stream>>>(bg, aL, aR, W1t, bgf1, W2c, bgf2,
                                         gg1, betag1, gg2, betag2, outbg);
}